// Round 3
// baseline (650.810 us; speedup 1.0000x reference)
//
#include <hip/hip_runtime.h>

#define B_ 4
#define L_ 4096
#define D_ 192
#define N_ 16
#define K_ 38
#define NC 64          // chunks per sequence
#define CH 64          // L_/NC
#define BLD (B_*L_*D_) // 3145728
#define LOG2E 1.44269504088896f

__device__ __forceinline__ float softplus_f(float z){
    // stable: max(z,0) + log(1+exp(-|z|))
    return fmaxf(z, 0.f) + __logf(1.f + __expf(-fabsf(z)));
}

// ---------------- P1: x_dbl[branch][b][l][38] (fp32 in ws) ----------------
// branch 0: x_rgb @ Wx1^T ; branch 1: x_e @ Wx2^T ; branch 2: (x_share_rgb+x_share_e) @ Wxs^T
__global__ __launch_bounds__(256) void proj_kernel(
    const float* __restrict__ xr,  const float* __restrict__ xsr,
    const float* __restrict__ xe,  const float* __restrict__ xse,
    const float* __restrict__ Wx1, const float* __restrict__ Wx2,
    const float* __restrict__ Wxs, float* __restrict__ xdbl)
{
    int t = threadIdx.x;
    if (t >= 228) return;                 // 6 rows * 38 outputs
    int gr = blockIdx.x * 6 + t / K_;     // global row = branch*(B*L) + b*L + l
    int k  = t % K_;
    int branch = gr / (B_ * L_);
    int row = gr - branch * (B_ * L_);
    const float* W = (branch == 0 ? Wx1 : branch == 1 ? Wx2 : Wxs) + (size_t)k * D_;
    float acc = 0.f;
    if (branch == 2){
        const float* xa = xsr + (size_t)row * D_;
        const float* xb = xse + (size_t)row * D_;
        #pragma unroll 8
        for (int i = 0; i < D_; i++)
            acc += (xa[i] + xb[i]) * W[i];
    } else {
        const float* x = (branch == 0 ? xr : xe) + (size_t)row * D_;
        #pragma unroll 8
        for (int i = 0; i < D_; i++)
            acc += x[i] * W[i];
    }
    xdbl[(size_t)gr * K_ + k] = acc;
}

// ---------------- Pass A: per-chunk local states S + delta-sums ----------------
// job 0: (delta,B from branch0, u=x_rgb)  -> inst 0
// job 1: (branch1, u=x_e)                 -> inst 1
// job 2: (branch2, u=x_rgb and x_e)       -> inst 2,3 (shared dA)
// S layout: [inst][b][c][d][16] fp32 ; dsum: [branch][b][c][d]
__global__ __launch_bounds__(192) void passA_kernel(
    const float* __restrict__ xdbl,
    const float* __restrict__ xr, const float* __restrict__ xe,
    const float* __restrict__ Wdt1, const float* __restrict__ Wdt2, const float* __restrict__ Wdts,
    const float* __restrict__ bdt1, const float* __restrict__ bdt2, const float* __restrict__ bdts,
    const float* __restrict__ Alog1, const float* __restrict__ Alog2, const float* __restrict__ Alogs,
    float* __restrict__ Sbuf, float* __restrict__ dsum)
{
    int blk = blockIdx.x;               // 0..767
    int job = blk >> 8;                 // /(B_*NC)=256
    int rem = blk & 255;
    int b = rem >> 6;
    int c = rem & 63;
    int d = threadIdx.x;
    const bool shared = (job == 2);

    const float* Wdt  = job == 0 ? Wdt1  : job == 1 ? Wdt2  : Wdts;
    const float* bdtp = job == 0 ? bdt1  : job == 1 ? bdt2  : bdts;
    const float* Alog = job == 0 ? Alog1 : job == 1 ? Alog2 : Alogs;

    float w[6];
    #pragma unroll
    for (int r = 0; r < 6; r++) w[r] = Wdt[d * 6 + r];
    float bd = bdtp[d];
    float A2[N_];
    #pragma unroll
    for (int n = 0; n < N_; n++) A2[n] = -__expf(Alog[d * N_ + n]) * LOG2E;

    float h[N_], h2[N_];
    #pragma unroll
    for (int n = 0; n < N_; n++){ h[n] = 0.f; h2[n] = 0.f; }
    float ds = 0.f;

    const float* u1 = (job == 1) ? xe : xr;
    const float* row = xdbl + ((size_t)(job * B_ + b) * L_ + (size_t)c * CH) * K_;
    size_t uoff = ((size_t)b * L_ + (size_t)c * CH) * D_ + d;

    for (int s = 0; s < CH; s++){
        float z = bd;
        #pragma unroll
        for (int r = 0; r < 6; r++) z += row[r] * w[r];
        float delta = softplus_f(z);
        ds += delta;
        float du = delta * u1[uoff];
        float du2 = shared ? delta * xe[uoff] : 0.f;
        #pragma unroll
        for (int n = 0; n < N_; n++){
            float dA = exp2f(delta * A2[n]);
            float bn = row[6 + n];
            h[n] = dA * h[n] + du * bn;
            if (shared) h2[n] = dA * h2[n] + du2 * bn;
        }
        row += K_;
        uoff += D_;
    }

    int inst = shared ? 2 : job;
    size_t sidx = ((((size_t)inst * B_ + b) * NC + c) * D_ + d) * N_;
    #pragma unroll
    for (int n = 0; n < N_; n += 4)
        *(float4*)(Sbuf + sidx + n) = make_float4(h[n], h[n+1], h[n+2], h[n+3]);
    if (shared){
        size_t sidx2 = ((((size_t)3 * B_ + b) * NC + c) * D_ + d) * N_;
        #pragma unroll
        for (int n = 0; n < N_; n += 4)
            *(float4*)(Sbuf + sidx2 + n) = make_float4(h2[n], h2[n+1], h2[n+2], h2[n+3]);
    }
    dsum[((size_t)(job * B_ + b) * NC + c) * D_ + d] = ds;
}

// ---------------- Combiner: sequential over chunks; converts Sbuf IN PLACE
// from per-chunk local end-states to per-chunk START states (hstart). ----------------
__global__ __launch_bounds__(256) void combine_kernel(
    float* __restrict__ Sbuf, const float* __restrict__ dsum,
    const float* __restrict__ Alog1, const float* __restrict__ Alog2, const float* __restrict__ Alogs)
{
    int tid = blockIdx.x * 256 + threadIdx.x;     // 0..3071 exactly (grid 12)
    int inst = tid / (B_ * D_);
    int rem = tid - inst * (B_ * D_);
    int b = rem / D_;
    int d = rem - b * D_;
    int branch = inst < 2 ? inst : 2;
    const float* Alog = inst == 0 ? Alog1 : inst == 1 ? Alog2 : Alogs;
    float A2[N_];
    #pragma unroll
    for (int n = 0; n < N_; n++) A2[n] = -__expf(Alog[d * N_ + n]) * LOG2E;
    float h[N_];
    #pragma unroll
    for (int n = 0; n < N_; n++) h[n] = 0.f;
    for (int c = 0; c < NC; c++){
        size_t idx = ((((size_t)inst * B_ + b) * NC + c) * D_ + d) * N_;
        float tmp[N_];
        #pragma unroll
        for (int n = 0; n < N_; n++) tmp[n] = Sbuf[idx + n];
        #pragma unroll
        for (int n = 0; n < N_; n += 4)
            *(float4*)(Sbuf + idx + n) = make_float4(h[n], h[n+1], h[n+2], h[n+3]);
        float dd = dsum[((size_t)(branch * B_ + b) * NC + c) * D_ + d];
        #pragma unroll
        for (int n = 0; n < N_; n++)
            h[n] = exp2f(A2[n] * dd) * h[n] + tmp[n];
    }
}

// ---------------- Pass C: full scan with h_start, y = sum h*C + D*u ----------------
// output order: [y_rgb][y_sh_rgb][y_e][y_sh_e]
__global__ __launch_bounds__(192) void passC_kernel(
    const float* __restrict__ xdbl,
    const float* __restrict__ xr, const float* __restrict__ xe,
    const float* __restrict__ Wdt1, const float* __restrict__ Wdt2, const float* __restrict__ Wdts,
    const float* __restrict__ bdt1, const float* __restrict__ bdt2, const float* __restrict__ bdts,
    const float* __restrict__ Alog1, const float* __restrict__ Alog2, const float* __restrict__ Alogs,
    const float* __restrict__ Dp1, const float* __restrict__ Dp2, const float* __restrict__ Dps,
    const float* __restrict__ hstart,
    float* __restrict__ out)
{
    int blk = blockIdx.x;
    int job = blk >> 8;
    int rem = blk & 255;
    int b = rem >> 6;
    int c = rem & 63;
    int d = threadIdx.x;
    const bool shared = (job == 2);

    const float* Wdt  = job == 0 ? Wdt1  : job == 1 ? Wdt2  : Wdts;
    const float* bdtp = job == 0 ? bdt1  : job == 1 ? bdt2  : bdts;
    const float* Alog = job == 0 ? Alog1 : job == 1 ? Alog2 : Alogs;
    float Dv = (job == 0 ? Dp1 : job == 1 ? Dp2 : Dps)[d];

    float w[6];
    #pragma unroll
    for (int r = 0; r < 6; r++) w[r] = Wdt[d * 6 + r];
    float bd = bdtp[d];
    float A2[N_];
    #pragma unroll
    for (int n = 0; n < N_; n++) A2[n] = -__expf(Alog[d * N_ + n]) * LOG2E;

    int inst = shared ? 2 : job;
    size_t hidx = ((((size_t)inst * B_ + b) * NC + c) * D_ + d) * N_;
    float h[N_], h2[N_];
    #pragma unroll
    for (int n = 0; n < N_; n++) h[n] = hstart[hidx + n];
    if (shared){
        size_t hidx2 = ((((size_t)3 * B_ + b) * NC + c) * D_ + d) * N_;
        #pragma unroll
        for (int n = 0; n < N_; n++) h2[n] = hstart[hidx2 + n];
    } else {
        #pragma unroll
        for (int n = 0; n < N_; n++) h2[n] = 0.f;
    }

    // C comes from the cross branch for jobs 0/1
    int cbranch = job == 0 ? 1 : job == 1 ? 0 : 2;
    const float* row  = xdbl + ((size_t)(job * B_ + b) * L_ + (size_t)c * CH) * K_;
    const float* crow = xdbl + ((size_t)(cbranch * B_ + b) * L_ + (size_t)c * CH) * K_ + 22;
    size_t uoff = ((size_t)b * L_ + (size_t)c * CH) * D_ + d;
    const float* u1 = (job == 1) ? xe : xr;
    size_t obase1 = job == 0 ? 0 : job == 1 ? (size_t)2 * BLD : (size_t)1 * BLD;

    for (int s = 0; s < CH; s++){
        float z = bd;
        #pragma unroll
        for (int r = 0; r < 6; r++) z += row[r] * w[r];
        float delta = softplus_f(z);
        float u1v = u1[uoff];
        float du = delta * u1v;
        float u2v = shared ? xe[uoff] : 0.f;
        float du2 = delta * u2v;
        float y = 0.f, y2 = 0.f;
        #pragma unroll
        for (int n = 0; n < N_; n++){
            float dA = exp2f(delta * A2[n]);
            float bn = row[6 + n];
            float cn = crow[n];
            h[n] = dA * h[n] + du * bn;
            y += h[n] * cn;
            if (shared){
                h2[n] = dA * h2[n] + du2 * bn;
                y2 += h2[n] * cn;
            }
        }
        out[obase1 + uoff] = y + Dv * u1v;
        if (shared) out[(size_t)3 * BLD + uoff] = y2 + Dv * u2v;
        row += K_; crow += K_;
        uoff += D_;
    }
}

// ---------------- LayerNorm in place on d_out (4 slots x [B][L][192]) ----------------
__global__ __launch_bounds__(256) void ln_kernel(
    float* __restrict__ out,
    const float* __restrict__ g1, const float* __restrict__ be1,
    const float* __restrict__ g2, const float* __restrict__ be2,
    const float* __restrict__ gs, const float* __restrict__ bes)
{
    int wave = threadIdx.x >> 6;
    int lane = threadIdx.x & 63;
    int rowg = blockIdx.x * 4 + wave;          // 0..65535
    int slot = rowg >> 14;                     // /(B_*L_)
    size_t base = (size_t)rowg * D_;
    const float* g  = slot == 0 ? g1  : slot == 2 ? g2  : gs;
    const float* be = slot == 0 ? be1 : slot == 2 ? be2 : bes;
    float x0 = out[base + lane];
    float x1 = out[base + lane + 64];
    float x2 = out[base + lane + 128];
    float s = x0 + x1 + x2;
    float q = x0*x0 + x1*x1 + x2*x2;
    #pragma unroll
    for (int o = 32; o > 0; o >>= 1){
        s += __shfl_xor(s, o);
        q += __shfl_xor(q, o);
    }
    float mean = s * (1.f / 192.f);
    float var  = q * (1.f / 192.f) - mean * mean;
    float rs = rsqrtf(var + 1e-5f);
    out[base + lane]       = (x0 - mean) * rs * g[lane]       + be[lane];
    out[base + lane + 64]  = (x1 - mean) * rs * g[lane + 64]  + be[lane + 64];
    out[base + lane + 128] = (x2 - mean) * rs * g[lane + 128] + be[lane + 128];
}

extern "C" void kernel_launch(void* const* d_in, const int* in_sizes, int n_in,
                              void* d_out, int out_size, void* d_ws, size_t ws_size,
                              hipStream_t stream)
{
    const float* xr   = (const float*)d_in[0];
    const float* xsr  = (const float*)d_in[1];
    const float* xe   = (const float*)d_in[2];
    const float* xse  = (const float*)d_in[3];
    const float* Wx1  = (const float*)d_in[4];
    const float* Wx2  = (const float*)d_in[5];
    const float* Wxs  = (const float*)d_in[6];
    const float* Wdt1 = (const float*)d_in[7];
    const float* Wdt2 = (const float*)d_in[8];
    const float* Wdts = (const float*)d_in[9];
    const float* bdt1 = (const float*)d_in[10];
    const float* bdt2 = (const float*)d_in[11];
    const float* bdts = (const float*)d_in[12];
    const float* Alog1= (const float*)d_in[13];
    const float* Alog2= (const float*)d_in[14];
    const float* Alogs= (const float*)d_in[15];
    const float* Dp1  = (const float*)d_in[16];
    const float* Dp2  = (const float*)d_in[17];
    const float* Dps  = (const float*)d_in[18];
    // setup_inputs() dict order: g1, g2, gs THEN be1, be2, bes
    const float* g1   = (const float*)d_in[19];
    const float* g2   = (const float*)d_in[20];
    const float* gs   = (const float*)d_in[21];
    const float* be1  = (const float*)d_in[22];
    const float* be2  = (const float*)d_in[23];
    const float* bes  = (const float*)d_in[24];

    float* ws = (float*)d_ws;
    float* xdbl   = ws;                                        // 3*B*L*38   = 1,867,776 f
    float* dsum   = xdbl + (size_t)3 * B_ * L_ * K_;           // 3*B*NC*D   =   147,456 f
    float* Sbuf   = dsum + (size_t)3 * B_ * NC * D_;           // 4*B*NC*D*16= 3,145,728 f (in-place -> hstart)
    float* out = (float*)d_out;

    proj_kernel<<<dim3(8192), dim3(256), 0, stream>>>(xr, xsr, xe, xse, Wx1, Wx2, Wxs, xdbl);
    passA_kernel<<<dim3(768), dim3(192), 0, stream>>>(xdbl, xr, xe,
        Wdt1, Wdt2, Wdts, bdt1, bdt2, bdts, Alog1, Alog2, Alogs, Sbuf, dsum);
    combine_kernel<<<dim3(12), dim3(256), 0, stream>>>(Sbuf, dsum, Alog1, Alog2, Alogs);
    passC_kernel<<<dim3(768), dim3(192), 0, stream>>>(xdbl, xr, xe,
        Wdt1, Wdt2, Wdts, bdt1, bdt2, bdts, Alog1, Alog2, Alogs,
        Dp1, Dp2, Dps, Sbuf, out);
    ln_kernel<<<dim3(16384), dim3(256), 0, stream>>>(out, g1, be1, g2, be2, gs, bes);
}

// Round 4
// 373.100 us; speedup vs baseline: 1.7443x; 1.7443x over previous
//
#include <hip/hip_runtime.h>

#define B_ 4
#define L_ 4096
#define D_ 192
#define N_ 16
#define K_ 38
#define NC 64          // chunks per sequence
#define CH 64          // L_/NC
#define BLD (B_*L_*D_) // 3145728
#define LOG2E 1.44269504088896f

__device__ __forceinline__ float fexp2(float x){ return __builtin_amdgcn_exp2f(x); }

__device__ __forceinline__ float softplus_f(float z){
    // stable: max(z,0) + log(1+exp(-|z|))
    return fmaxf(z, 0.f) + __logf(1.f + __expf(-fabsf(z)));
}

// ---------------- P1: x_dbl[branch][b][l][38] (fp32 in ws) ----------------
// thread = one row; acc[38] in VGPRs; W loads wave-uniform -> scalar cache.
// branch uniform per block: grid 768 blocks of 64, branch = blockIdx >> 8.
__global__ __launch_bounds__(64) void proj_kernel(
    const float* __restrict__ xr,  const float* __restrict__ xsr,
    const float* __restrict__ xe,  const float* __restrict__ xse,
    const float* __restrict__ Wx1, const float* __restrict__ Wx2,
    const float* __restrict__ Wxs, float* __restrict__ xdbl)
{
    int gr = blockIdx.x * 64 + threadIdx.x;   // global row 0..49151
    int branch = blockIdx.x >> 8;             // uniform (16384/64 = 256 blocks/branch)
    int row = gr & 16383;

    const float* W = (branch == 0 ? Wx1 : branch == 1 ? Wx2 : Wxs);
    const float4* W4 = (const float4*)W;      // (c,kq) at W4[c*48+kq]
    const float4* x4a;
    const float4* x4b = nullptr;
    if (branch == 0)      x4a = (const float4*)(xr  + (size_t)row * D_);
    else if (branch == 1) x4a = (const float4*)(xe  + (size_t)row * D_);
    else { x4a = (const float4*)(xsr + (size_t)row * D_);
           x4b = (const float4*)(xse + (size_t)row * D_); }

    float acc[K_];
    #pragma unroll
    for (int c = 0; c < K_; c++) acc[c] = 0.f;

    #pragma unroll 2
    for (int kq = 0; kq < 48; kq++){
        float4 xv = x4a[kq];
        if (branch == 2){
            float4 t = x4b[kq];
            xv.x += t.x; xv.y += t.y; xv.z += t.z; xv.w += t.w;
        }
        #pragma unroll
        for (int c = 0; c < K_; c++){
            float4 wv = W4[c * 48 + kq];      // uniform address -> s_load_dwordx4
            acc[c] = fmaf(xv.x, wv.x, fmaf(xv.y, wv.y,
                     fmaf(xv.z, wv.z, fmaf(xv.w, wv.w, acc[c]))));
        }
    }
    float* o = xdbl + (size_t)gr * K_;
    #pragma unroll
    for (int c = 0; c < K_; c++) o[c] = acc[c];
}

// ---------------- Pass A: per-chunk local states S + delta-sums ----------------
// job 0: (delta,B from branch0, u=x_rgb)  -> inst 0
// job 1: (branch1, u=x_e)                 -> inst 1
// job 2: (branch2, u=x_rgb and x_e)       -> inst 2,3 (shared dA)
// S layout: [inst][b][c][d][16] fp32 ; dsum: [branch][b][c][d]
__global__ __launch_bounds__(192) void passA_kernel(
    const float* __restrict__ xdbl,
    const float* __restrict__ xr, const float* __restrict__ xe,
    const float* __restrict__ Wdt1, const float* __restrict__ Wdt2, const float* __restrict__ Wdts,
    const float* __restrict__ bdt1, const float* __restrict__ bdt2, const float* __restrict__ bdts,
    const float* __restrict__ Alog1, const float* __restrict__ Alog2, const float* __restrict__ Alogs,
    float* __restrict__ Sbuf, float* __restrict__ dsum)
{
    int blk = blockIdx.x;               // 0..767
    int job = blk >> 8;
    int rem = blk & 255;
    int b = rem >> 6;
    int c = rem & 63;
    int d = threadIdx.x;
    const bool shared = (job == 2);

    const float* Wdt  = job == 0 ? Wdt1  : job == 1 ? Wdt2  : Wdts;
    const float* bdtp = job == 0 ? bdt1  : job == 1 ? bdt2  : bdts;
    const float* Alog = job == 0 ? Alog1 : job == 1 ? Alog2 : Alogs;

    float w[6];
    #pragma unroll
    for (int r = 0; r < 6; r++) w[r] = Wdt[d * 6 + r];
    float bd = bdtp[d];
    float A2[N_];
    #pragma unroll
    for (int n = 0; n < N_; n++) A2[n] = -__expf(Alog[d * N_ + n]) * LOG2E;

    float h[N_], h2[N_];
    #pragma unroll
    for (int n = 0; n < N_; n++){ h[n] = 0.f; h2[n] = 0.f; }
    float ds = 0.f;

    const float* u1 = (job == 1) ? xe : xr;
    const float* row = xdbl + ((size_t)(job * B_ + b) * L_ + (size_t)c * CH) * K_;
    size_t uoff = ((size_t)b * L_ + (size_t)c * CH) * D_ + d;

    // software pipeline: one-step lookahead (row over-read past chunk end
    // lands in dsum region of ws -- valid memory, values unused)
    float cur[22];
    #pragma unroll
    for (int i = 0; i < 22; i++) cur[i] = row[i];
    float uv  = u1[uoff];
    float uv2 = shared ? xe[uoff] : 0.f;

    for (int s = 0; s < CH; s++){
        float nxt[22];
        #pragma unroll
        for (int i = 0; i < 22; i++) nxt[i] = row[K_ + i];
        size_t uoff_n = uoff + (s + 1 < CH ? (size_t)D_ : 0);
        float uv_n  = u1[uoff_n];
        float uv2_n = shared ? xe[uoff_n] : 0.f;

        float z = bd;
        #pragma unroll
        for (int r = 0; r < 6; r++) z = fmaf(cur[r], w[r], z);
        float delta = softplus_f(z);
        ds += delta;
        float du  = delta * uv;
        float du2 = delta * uv2;
        #pragma unroll
        for (int n = 0; n < N_; n++){
            float dA = fexp2(delta * A2[n]);
            float bn = cur[6 + n];
            h[n] = fmaf(dA, h[n], du * bn);
            if (shared) h2[n] = fmaf(dA, h2[n], du2 * bn);
        }
        row += K_;
        #pragma unroll
        for (int i = 0; i < 22; i++) cur[i] = nxt[i];
        uv = uv_n; uv2 = uv2_n; uoff = uoff_n;
    }

    int inst = shared ? 2 : job;
    size_t sidx = ((((size_t)inst * B_ + b) * NC + c) * D_ + d) * N_;
    #pragma unroll
    for (int n = 0; n < N_; n += 4)
        *(float4*)(Sbuf + sidx + n) = make_float4(h[n], h[n+1], h[n+2], h[n+3]);
    if (shared){
        size_t sidx2 = ((((size_t)3 * B_ + b) * NC + c) * D_ + d) * N_;
        #pragma unroll
        for (int n = 0; n < N_; n += 4)
            *(float4*)(Sbuf + sidx2 + n) = make_float4(h2[n], h2[n+1], h2[n+2], h2[n+3]);
    }
    dsum[((size_t)(job * B_ + b) * NC + c) * D_ + d] = ds;
}

// ---------------- Combiner: thread per (inst,b,d,n); sequential over chunks.
// Converts Sbuf IN PLACE from per-chunk local end-states to chunk START states.
__global__ __launch_bounds__(256) void combine_kernel(
    float* __restrict__ Sbuf, const float* __restrict__ dsum,
    const float* __restrict__ Alog1, const float* __restrict__ Alog2, const float* __restrict__ Alogs)
{
    int tid = blockIdx.x * 256 + threadIdx.x;     // 0..49151 (grid 192)
    int inst = tid / (B_ * D_ * N_);              // /12288, uniform per block
    int rem  = tid - inst * (B_ * D_ * N_);
    int b  = rem / (D_ * N_);
    int dn = rem - b * (D_ * N_);
    int d = dn >> 4;
    int n = dn & 15;
    int branch = inst < 2 ? inst : 2;
    const float* Alog = inst == 0 ? Alog1 : inst == 1 ? Alog2 : Alogs;
    float A2 = -__expf(Alog[d * N_ + n]) * LOG2E;

    float h = 0.f;
    size_t base  = (((size_t)inst * B_ + b) * NC) * (D_ * N_) + dn;   // + c*D_*N_
    size_t dbase = (((size_t)branch * B_ + b) * NC) * D_ + d;         // + c*D_
    for (int c = 0; c < NC; c++){
        size_t idx = base + (size_t)c * (D_ * N_);
        float S = Sbuf[idx];
        Sbuf[idx] = h;
        float dd = dsum[dbase + (size_t)c * D_];
        h = fmaf(fexp2(A2 * dd), h, S);
    }
}

// ---------------- Pass C: full scan with h_start, y = sum h*C + D*u ----------------
// output order: [y_rgb][y_sh_rgb][y_e][y_sh_e]
__global__ __launch_bounds__(192) void passC_kernel(
    const float* __restrict__ xdbl,
    const float* __restrict__ xr, const float* __restrict__ xe,
    const float* __restrict__ Wdt1, const float* __restrict__ Wdt2, const float* __restrict__ Wdts,
    const float* __restrict__ bdt1, const float* __restrict__ bdt2, const float* __restrict__ bdts,
    const float* __restrict__ Alog1, const float* __restrict__ Alog2, const float* __restrict__ Alogs,
    const float* __restrict__ Dp1, const float* __restrict__ Dp2, const float* __restrict__ Dps,
    const float* __restrict__ hstart,
    float* __restrict__ out)
{
    int blk = blockIdx.x;
    int job = blk >> 8;
    int rem = blk & 255;
    int b = rem >> 6;
    int c = rem & 63;
    int d = threadIdx.x;
    const bool shared = (job == 2);

    const float* Wdt  = job == 0 ? Wdt1  : job == 1 ? Wdt2  : Wdts;
    const float* bdtp = job == 0 ? bdt1  : job == 1 ? bdt2  : bdts;
    const float* Alog = job == 0 ? Alog1 : job == 1 ? Alog2 : Alogs;
    float Dv = (job == 0 ? Dp1 : job == 1 ? Dp2 : Dps)[d];

    float w[6];
    #pragma unroll
    for (int r = 0; r < 6; r++) w[r] = Wdt[d * 6 + r];
    float bd = bdtp[d];
    float A2[N_];
    #pragma unroll
    for (int n = 0; n < N_; n++) A2[n] = -__expf(Alog[d * N_ + n]) * LOG2E;

    int inst = shared ? 2 : job;
    size_t hidx = ((((size_t)inst * B_ + b) * NC + c) * D_ + d) * N_;
    float h[N_], h2[N_];
    #pragma unroll
    for (int n = 0; n < N_; n++) h[n] = hstart[hidx + n];
    if (shared){
        size_t hidx2 = ((((size_t)3 * B_ + b) * NC + c) * D_ + d) * N_;
        #pragma unroll
        for (int n = 0; n < N_; n++) h2[n] = hstart[hidx2 + n];
    } else {
        #pragma unroll
        for (int n = 0; n < N_; n++) h2[n] = 0.f;
    }

    // C comes from the cross branch for jobs 0/1
    int cbranch = job == 0 ? 1 : job == 1 ? 0 : 2;
    const float* row  = xdbl + ((size_t)(job * B_ + b) * L_ + (size_t)c * CH) * K_;
    const float* crow = xdbl + ((size_t)(cbranch * B_ + b) * L_ + (size_t)c * CH) * K_ + 22;
    size_t uoff = ((size_t)b * L_ + (size_t)c * CH) * D_ + d;
    const float* u1 = (job == 1) ? xe : xr;
    size_t obase1 = job == 0 ? 0 : job == 1 ? (size_t)2 * BLD : (size_t)1 * BLD;

    float cur[22], curC[N_];
    #pragma unroll
    for (int i = 0; i < 22; i++) cur[i] = row[i];
    #pragma unroll
    for (int n = 0; n < N_; n++) curC[n] = crow[n];
    float uv  = u1[uoff];
    float uv2 = shared ? xe[uoff] : 0.f;

    for (int s = 0; s < CH; s++){
        float nxt[22], nxtC[N_];
        #pragma unroll
        for (int i = 0; i < 22; i++) nxt[i] = row[K_ + i];
        #pragma unroll
        for (int n = 0; n < N_; n++) nxtC[n] = crow[K_ + n];
        size_t uoff_n = uoff + (s + 1 < CH ? (size_t)D_ : 0);
        float uv_n  = u1[uoff_n];
        float uv2_n = shared ? xe[uoff_n] : 0.f;

        float z = bd;
        #pragma unroll
        for (int r = 0; r < 6; r++) z = fmaf(cur[r], w[r], z);
        float delta = softplus_f(z);
        float du  = delta * uv;
        float du2 = delta * uv2;
        float y = 0.f, y2 = 0.f;
        #pragma unroll
        for (int n = 0; n < N_; n++){
            float dA = fexp2(delta * A2[n]);
            float bn = cur[6 + n];
            float cn = curC[n];
            h[n] = fmaf(dA, h[n], du * bn);
            y = fmaf(h[n], cn, y);
            if (shared){
                h2[n] = fmaf(dA, h2[n], du2 * bn);
                y2 = fmaf(h2[n], cn, y2);
            }
        }
        out[obase1 + uoff] = fmaf(Dv, uv, y);
        if (shared) out[(size_t)3 * BLD + uoff] = fmaf(Dv, uv2, y2);

        row += K_; crow += K_;
        #pragma unroll
        for (int i = 0; i < 22; i++) cur[i] = nxt[i];
        #pragma unroll
        for (int n = 0; n < N_; n++) curC[n] = nxtC[n];
        uv = uv_n; uv2 = uv2_n; uoff = uoff_n;
    }
}

// ---------------- LayerNorm in place on d_out (4 slots x [B][L][192]) ----------------
__global__ __launch_bounds__(256) void ln_kernel(
    float* __restrict__ out,
    const float* __restrict__ g1, const float* __restrict__ be1,
    const float* __restrict__ g2, const float* __restrict__ be2,
    const float* __restrict__ gs, const float* __restrict__ bes)
{
    int wave = threadIdx.x >> 6;
    int lane = threadIdx.x & 63;
    int rowg = blockIdx.x * 4 + wave;          // 0..65535
    int slot = rowg >> 14;                     // /(B_*L_)
    size_t base = (size_t)rowg * D_;
    const float* g  = slot == 0 ? g1  : slot == 2 ? g2  : gs;
    const float* be = slot == 0 ? be1 : slot == 2 ? be2 : bes;
    float x0 = out[base + lane];
    float x1 = out[base + lane + 64];
    float x2 = out[base + lane + 128];
    float s = x0 + x1 + x2;
    float q = x0*x0 + x1*x1 + x2*x2;
    #pragma unroll
    for (int o = 32; o > 0; o >>= 1){
        s += __shfl_xor(s, o);
        q += __shfl_xor(q, o);
    }
    float mean = s * (1.f / 192.f);
    float var  = q * (1.f / 192.f) - mean * mean;
    float rs = rsqrtf(var + 1e-5f);
    out[base + lane]       = (x0 - mean) * rs * g[lane]       + be[lane];
    out[base + lane + 64]  = (x1 - mean) * rs * g[lane + 64]  + be[lane + 64];
    out[base + lane + 128] = (x2 - mean) * rs * g[lane + 128] + be[lane + 128];
}

extern "C" void kernel_launch(void* const* d_in, const int* in_sizes, int n_in,
                              void* d_out, int out_size, void* d_ws, size_t ws_size,
                              hipStream_t stream)
{
    const float* xr   = (const float*)d_in[0];
    const float* xsr  = (const float*)d_in[1];
    const float* xe   = (const float*)d_in[2];
    const float* xse  = (const float*)d_in[3];
    const float* Wx1  = (const float*)d_in[4];
    const float* Wx2  = (const float*)d_in[5];
    const float* Wxs  = (const float*)d_in[6];
    const float* Wdt1 = (const float*)d_in[7];
    const float* Wdt2 = (const float*)d_in[8];
    const float* Wdts = (const float*)d_in[9];
    const float* bdt1 = (const float*)d_in[10];
    const float* bdt2 = (const float*)d_in[11];
    const float* bdts = (const float*)d_in[12];
    const float* Alog1= (const float*)d_in[13];
    const float* Alog2= (const float*)d_in[14];
    const float* Alogs= (const float*)d_in[15];
    const float* Dp1  = (const float*)d_in[16];
    const float* Dp2  = (const float*)d_in[17];
    const float* Dps  = (const float*)d_in[18];
    // setup_inputs() dict order: g1, g2, gs THEN be1, be2, bes
    const float* g1   = (const float*)d_in[19];
    const float* g2   = (const float*)d_in[20];
    const float* gs   = (const float*)d_in[21];
    const float* be1  = (const float*)d_in[22];
    const float* be2  = (const float*)d_in[23];
    const float* bes  = (const float*)d_in[24];

    float* ws = (float*)d_ws;
    float* xdbl   = ws;                                        // 3*B*L*38   = 1,867,776 f
    float* dsum   = xdbl + (size_t)3 * B_ * L_ * K_;           // 3*B*NC*D   =   147,456 f
    float* Sbuf   = dsum + (size_t)3 * B_ * NC * D_;           // 4*B*NC*D*16= 3,145,728 f (in-place -> hstart)
    float* out = (float*)d_out;

    proj_kernel<<<dim3(768), dim3(64), 0, stream>>>(xr, xsr, xe, xse, Wx1, Wx2, Wxs, xdbl);
    passA_kernel<<<dim3(768), dim3(192), 0, stream>>>(xdbl, xr, xe,
        Wdt1, Wdt2, Wdts, bdt1, bdt2, bdts, Alog1, Alog2, Alogs, Sbuf, dsum);
    combine_kernel<<<dim3(192), dim3(256), 0, stream>>>(Sbuf, dsum, Alog1, Alog2, Alogs);
    passC_kernel<<<dim3(768), dim3(192), 0, stream>>>(xdbl, xr, xe,
        Wdt1, Wdt2, Wdts, bdt1, bdt2, bdts, Alog1, Alog2, Alogs,
        Dp1, Dp2, Dps, Sbuf, out);
    ln_kernel<<<dim3(16384), dim3(256), 0, stream>>>(out, g1, be1, g2, be2, gs, bes);
}

// Round 5
// 368.098 us; speedup vs baseline: 1.7680x; 1.0136x over previous
//
#include <hip/hip_runtime.h>

#define B_ 4
#define L_ 4096
#define D_ 192
#define N_ 16
#define K_ 38
#define BLD (B_*L_*D_) // 3145728
#define LOG2E 1.44269504088896f

__device__ __forceinline__ float fexp2(float x){ return __builtin_amdgcn_exp2f(x); }

__device__ __forceinline__ float softplus_f(float z){
    // stable: max(z,0) + log(1+exp(-|z|))
    return fmaxf(z, 0.f) + __logf(1.f + __expf(-fabsf(z)));
}

// ---------------- P1: x_dbl[branch][b][l][38] (fp32 in ws) ----------------
// 768 blocks x 512 threads. Block = (branch, 64-row tile); wave w of 8 owns a
// <=5-column slice (wave-uniform -> W via scalar loads); lane = row in tile.
// 6144 waves = 24/CU for latency hiding; x float4 loads shared via L1/L2.
__global__ __launch_bounds__(512) void proj_kernel(
    const float* __restrict__ xr,  const float* __restrict__ xsr,
    const float* __restrict__ xe,  const float* __restrict__ xse,
    const float* __restrict__ Wx1, const float* __restrict__ Wx2,
    const float* __restrict__ Wxs, float* __restrict__ xdbl)
{
    int branch = blockIdx.x >> 8;             // 0..2, uniform
    int tile   = blockIdx.x & 255;
    int lane = threadIdx.x & 63;
    int wv   = threadIdx.x >> 6;              // 0..7, wave-uniform
    int row  = tile * 64 + lane;              // 0..16383
    int gr   = branch * (B_ * L_) + row;

    int c0 = wv * 5;
    int ncols = (c0 + 5 <= K_) ? 5 : (K_ - c0);   // waves 0-6: 5, wave 7: 3

    const float* W = (branch == 0 ? Wx1 : branch == 1 ? Wx2 : Wxs);
    const float4* W4 = (const float4*)W;      // W4[c*48 + kq]
    const float4* x4a;
    const float4* x4b = nullptr;
    if (branch == 0)      x4a = (const float4*)(xr  + (size_t)row * D_);
    else if (branch == 1) x4a = (const float4*)(xe  + (size_t)row * D_);
    else { x4a = (const float4*)(xsr + (size_t)row * D_);
           x4b = (const float4*)(xse + (size_t)row * D_); }

    float acc[5];
    #pragma unroll
    for (int j = 0; j < 5; j++) acc[j] = 0.f;

    #pragma unroll 4
    for (int kq = 0; kq < 48; kq++){
        float4 xv = x4a[kq];
        if (branch == 2){
            float4 t = x4b[kq];
            xv.x += t.x; xv.y += t.y; xv.z += t.z; xv.w += t.w;
        }
        #pragma unroll
        for (int j = 0; j < 5; j++){
            if (j < ncols){
                float4 wv4 = W4[(c0 + j) * 48 + kq];   // wave-uniform -> s_load
                acc[j] = fmaf(xv.x, wv4.x, fmaf(xv.y, wv4.y,
                         fmaf(xv.z, wv4.z, fmaf(xv.w, wv4.w, acc[j]))));
            }
        }
    }
    float* o = xdbl + (size_t)gr * K_ + c0;
    #pragma unroll
    for (int j = 0; j < 5; j++)
        if (j < ncols) o[j] = acc[j];
}

// ---------------- Pass A: per-chunk local states S + delta-sums ----------------
// job 0: (delta,B from branch0, u=x_rgb)  -> inst 0
// job 1: (branch1, u=x_e)                 -> inst 1
// job 2: (branch2, u=x_rgb and x_e)       -> inst 2,3 (shared dA)
// S layout: [inst][b][c][d][16] fp32 ; dsum: [branch][b][c][d]
template<int NCt>
__global__ __launch_bounds__(192) void passA_kernel(
    const float* __restrict__ xdbl,
    const float* __restrict__ xr, const float* __restrict__ xe,
    const float* __restrict__ Wdt1, const float* __restrict__ Wdt2, const float* __restrict__ Wdts,
    const float* __restrict__ bdt1, const float* __restrict__ bdt2, const float* __restrict__ bdts,
    const float* __restrict__ Alog1, const float* __restrict__ Alog2, const float* __restrict__ Alogs,
    float* __restrict__ Sbuf, float* __restrict__ dsum)
{
    constexpr int CHt = L_ / NCt;
    int blk = blockIdx.x;               // 0..3*B_*NCt-1
    int job = blk / (B_ * NCt);
    int rem = blk - job * (B_ * NCt);
    int b = rem / NCt;
    int c = rem - b * NCt;
    int d = threadIdx.x;
    const bool shared = (job == 2);

    const float* Wdt  = job == 0 ? Wdt1  : job == 1 ? Wdt2  : Wdts;
    const float* bdtp = job == 0 ? bdt1  : job == 1 ? bdt2  : bdts;
    const float* Alog = job == 0 ? Alog1 : job == 1 ? Alog2 : Alogs;

    float w[6];
    #pragma unroll
    for (int r = 0; r < 6; r++) w[r] = Wdt[d * 6 + r];
    float bd = bdtp[d];
    float A2[N_];
    #pragma unroll
    for (int n = 0; n < N_; n++) A2[n] = -__expf(Alog[d * N_ + n]) * LOG2E;

    float h[N_], h2[N_];
    #pragma unroll
    for (int n = 0; n < N_; n++){ h[n] = 0.f; h2[n] = 0.f; }
    float ds = 0.f;

    const float* u1 = (job == 1) ? xe : xr;
    const float* row = xdbl + ((size_t)(job * B_ + b) * L_ + (size_t)c * CHt) * K_;
    size_t uoff = ((size_t)b * L_ + (size_t)c * CHt) * D_ + d;

    // software pipeline: one-step lookahead (row over-read past chunk end
    // lands in dsum region of ws -- valid memory, values unused)
    float cur[22];
    #pragma unroll
    for (int i = 0; i < 22; i++) cur[i] = row[i];
    float uv  = u1[uoff];
    float uv2 = shared ? xe[uoff] : 0.f;

    for (int s = 0; s < CHt; s++){
        float nxt[22];
        #pragma unroll
        for (int i = 0; i < 22; i++) nxt[i] = row[K_ + i];
        size_t uoff_n = uoff + (s + 1 < CHt ? (size_t)D_ : 0);
        float uv_n  = u1[uoff_n];
        float uv2_n = shared ? xe[uoff_n] : 0.f;

        float z = bd;
        #pragma unroll
        for (int r = 0; r < 6; r++) z = fmaf(cur[r], w[r], z);
        float delta = softplus_f(z);
        ds += delta;
        float du  = delta * uv;
        float du2 = delta * uv2;
        #pragma unroll
        for (int n = 0; n < N_; n++){
            float dA = fexp2(delta * A2[n]);
            float bn = cur[6 + n];
            h[n] = fmaf(dA, h[n], du * bn);
            if (shared) h2[n] = fmaf(dA, h2[n], du2 * bn);
        }
        row += K_;
        #pragma unroll
        for (int i = 0; i < 22; i++) cur[i] = nxt[i];
        uv = uv_n; uv2 = uv2_n; uoff = uoff_n;
    }

    int inst = shared ? 2 : job;
    size_t sidx = ((((size_t)inst * B_ + b) * NCt + c) * D_ + d) * N_;
    #pragma unroll
    for (int n = 0; n < N_; n += 4)
        *(float4*)(Sbuf + sidx + n) = make_float4(h[n], h[n+1], h[n+2], h[n+3]);
    if (shared){
        size_t sidx2 = ((((size_t)3 * B_ + b) * NCt + c) * D_ + d) * N_;
        #pragma unroll
        for (int n = 0; n < N_; n += 4)
            *(float4*)(Sbuf + sidx2 + n) = make_float4(h2[n], h2[n+1], h2[n+2], h2[n+3]);
    }
    dsum[((size_t)(job * B_ + b) * NCt + c) * D_ + d] = ds;
}

// ---------------- Combiner: thread per (inst,b,d,n); sequential over chunks.
// Converts Sbuf IN PLACE from per-chunk local end-states to chunk START states.
template<int NCt>
__global__ __launch_bounds__(256) void combine_kernel(
    float* __restrict__ Sbuf, const float* __restrict__ dsum,
    const float* __restrict__ Alog1, const float* __restrict__ Alog2, const float* __restrict__ Alogs)
{
    int tid = blockIdx.x * 256 + threadIdx.x;     // 0..49151 (grid 192)
    int inst = tid / (B_ * D_ * N_);              // uniform per block
    int rem  = tid - inst * (B_ * D_ * N_);
    int b  = rem / (D_ * N_);
    int dn = rem - b * (D_ * N_);
    int d = dn >> 4;
    int n = dn & 15;
    int branch = inst < 2 ? inst : 2;
    const float* Alog = inst == 0 ? Alog1 : inst == 1 ? Alog2 : Alogs;
    float A2 = -__expf(Alog[d * N_ + n]) * LOG2E;

    float h = 0.f;
    size_t base  = (((size_t)inst * B_ + b) * NCt) * (D_ * N_) + dn;   // + c*D_*N_
    size_t dbase = (((size_t)branch * B_ + b) * NCt) * D_ + d;         // + c*D_
    for (int c = 0; c < NCt; c++){
        size_t idx = base + (size_t)c * (D_ * N_);
        float S = Sbuf[idx];
        Sbuf[idx] = h;
        float dd = dsum[dbase + (size_t)c * D_];
        h = fmaf(fexp2(A2 * dd), h, S);
    }
}

// ---------------- Pass C: full scan with h_start, y = sum h*C + D*u ----------------
// output order: [y_rgb][y_sh_rgb][y_e][y_sh_e]
template<int NCt>
__global__ __launch_bounds__(192) void passC_kernel(
    const float* __restrict__ xdbl,
    const float* __restrict__ xr, const float* __restrict__ xe,
    const float* __restrict__ Wdt1, const float* __restrict__ Wdt2, const float* __restrict__ Wdts,
    const float* __restrict__ bdt1, const float* __restrict__ bdt2, const float* __restrict__ bdts,
    const float* __restrict__ Alog1, const float* __restrict__ Alog2, const float* __restrict__ Alogs,
    const float* __restrict__ Dp1, const float* __restrict__ Dp2, const float* __restrict__ Dps,
    const float* __restrict__ hstart,
    float* __restrict__ out)
{
    constexpr int CHt = L_ / NCt;
    int blk = blockIdx.x;
    int job = blk / (B_ * NCt);
    int rem = blk - job * (B_ * NCt);
    int b = rem / NCt;
    int c = rem - b * NCt;
    int d = threadIdx.x;
    const bool shared = (job == 2);

    const float* Wdt  = job == 0 ? Wdt1  : job == 1 ? Wdt2  : Wdts;
    const float* bdtp = job == 0 ? bdt1  : job == 1 ? bdt2  : bdts;
    const float* Alog = job == 0 ? Alog1 : job == 1 ? Alog2 : Alogs;
    float Dv = (job == 0 ? Dp1 : job == 1 ? Dp2 : Dps)[d];

    float w[6];
    #pragma unroll
    for (int r = 0; r < 6; r++) w[r] = Wdt[d * 6 + r];
    float bd = bdtp[d];
    float A2[N_];
    #pragma unroll
    for (int n = 0; n < N_; n++) A2[n] = -__expf(Alog[d * N_ + n]) * LOG2E;

    int inst = shared ? 2 : job;
    size_t hidx = ((((size_t)inst * B_ + b) * NCt + c) * D_ + d) * N_;
    float h[N_], h2[N_];
    #pragma unroll
    for (int n = 0; n < N_; n++) h[n] = hstart[hidx + n];
    if (shared){
        size_t hidx2 = ((((size_t)3 * B_ + b) * NCt + c) * D_ + d) * N_;
        #pragma unroll
        for (int n = 0; n < N_; n++) h2[n] = hstart[hidx2 + n];
    } else {
        #pragma unroll
        for (int n = 0; n < N_; n++) h2[n] = 0.f;
    }

    // C comes from the cross branch for jobs 0/1
    int cbranch = job == 0 ? 1 : job == 1 ? 0 : 2;
    const float* row  = xdbl + ((size_t)(job * B_ + b) * L_ + (size_t)c * CHt) * K_;
    const float* crow = xdbl + ((size_t)(cbranch * B_ + b) * L_ + (size_t)c * CHt) * K_ + 22;
    size_t uoff = ((size_t)b * L_ + (size_t)c * CHt) * D_ + d;
    const float* u1 = (job == 1) ? xe : xr;
    size_t obase1 = job == 0 ? 0 : job == 1 ? (size_t)2 * BLD : (size_t)1 * BLD;

    float cur[22], curC[N_];
    #pragma unroll
    for (int i = 0; i < 22; i++) cur[i] = row[i];
    #pragma unroll
    for (int n = 0; n < N_; n++) curC[n] = crow[n];
    float uv  = u1[uoff];
    float uv2 = shared ? xe[uoff] : 0.f;

    for (int s = 0; s < CHt; s++){
        float nxt[22], nxtC[N_];
        #pragma unroll
        for (int i = 0; i < 22; i++) nxt[i] = row[K_ + i];
        #pragma unroll
        for (int n = 0; n < N_; n++) nxtC[n] = crow[K_ + n];
        size_t uoff_n = uoff + (s + 1 < CHt ? (size_t)D_ : 0);
        float uv_n  = u1[uoff_n];
        float uv2_n = shared ? xe[uoff_n] : 0.f;

        float z = bd;
        #pragma unroll
        for (int r = 0; r < 6; r++) z = fmaf(cur[r], w[r], z);
        float delta = softplus_f(z);
        float du  = delta * uv;
        float du2 = delta * uv2;
        float y = 0.f, y2 = 0.f;
        #pragma unroll
        for (int n = 0; n < N_; n++){
            float dA = fexp2(delta * A2[n]);
            float bn = cur[6 + n];
            float cn = curC[n];
            h[n] = fmaf(dA, h[n], du * bn);
            y = fmaf(h[n], cn, y);
            if (shared){
                h2[n] = fmaf(dA, h2[n], du2 * bn);
                y2 = fmaf(h2[n], cn, y2);
            }
        }
        out[obase1 + uoff] = fmaf(Dv, uv, y);
        if (shared) out[(size_t)3 * BLD + uoff] = fmaf(Dv, uv2, y2);

        row += K_; crow += K_;
        #pragma unroll
        for (int i = 0; i < 22; i++) cur[i] = nxt[i];
        #pragma unroll
        for (int n = 0; n < N_; n++) curC[n] = nxtC[n];
        uv = uv_n; uv2 = uv2_n; uoff = uoff_n;
    }
}

// ---------------- LayerNorm in place on d_out (4 slots x [B][L][192]) ----------------
__global__ __launch_bounds__(256) void ln_kernel(
    float* __restrict__ out,
    const float* __restrict__ g1, const float* __restrict__ be1,
    const float* __restrict__ g2, const float* __restrict__ be2,
    const float* __restrict__ gs, const float* __restrict__ bes)
{
    int wave = threadIdx.x >> 6;
    int lane = threadIdx.x & 63;
    int rowg = blockIdx.x * 4 + wave;          // 0..65535
    int slot = rowg >> 14;                     // /(B_*L_)
    size_t base = (size_t)rowg * D_;
    const float* g  = slot == 0 ? g1  : slot == 2 ? g2  : gs;
    const float* be = slot == 0 ? be1 : slot == 2 ? be2 : bes;
    float x0 = out[base + lane];
    float x1 = out[base + lane + 64];
    float x2 = out[base + lane + 128];
    float s = x0 + x1 + x2;
    float q = x0*x0 + x1*x1 + x2*x2;
    #pragma unroll
    for (int o = 32; o > 0; o >>= 1){
        s += __shfl_xor(s, o);
        q += __shfl_xor(q, o);
    }
    float mean = s * (1.f / 192.f);
    float var  = q * (1.f / 192.f) - mean * mean;
    float rs = rsqrtf(var + 1e-5f);
    out[base + lane]       = (x0 - mean) * rs * g[lane]       + be[lane];
    out[base + lane + 64]  = (x1 - mean) * rs * g[lane + 64]  + be[lane + 64];
    out[base + lane + 128] = (x2 - mean) * rs * g[lane + 128] + be[lane + 128];
}

extern "C" void kernel_launch(void* const* d_in, const int* in_sizes, int n_in,
                              void* d_out, int out_size, void* d_ws, size_t ws_size,
                              hipStream_t stream)
{
    const float* xr   = (const float*)d_in[0];
    const float* xsr  = (const float*)d_in[1];
    const float* xe   = (const float*)d_in[2];
    const float* xse  = (const float*)d_in[3];
    const float* Wx1  = (const float*)d_in[4];
    const float* Wx2  = (const float*)d_in[5];
    const float* Wxs  = (const float*)d_in[6];
    const float* Wdt1 = (const float*)d_in[7];
    const float* Wdt2 = (const float*)d_in[8];
    const float* Wdts = (const float*)d_in[9];
    const float* bdt1 = (const float*)d_in[10];
    const float* bdt2 = (const float*)d_in[11];
    const float* bdts = (const float*)d_in[12];
    const float* Alog1= (const float*)d_in[13];
    const float* Alog2= (const float*)d_in[14];
    const float* Alogs= (const float*)d_in[15];
    const float* Dp1  = (const float*)d_in[16];
    const float* Dp2  = (const float*)d_in[17];
    const float* Dps  = (const float*)d_in[18];
    // setup_inputs() dict order: g1, g2, gs THEN be1, be2, bes
    const float* g1   = (const float*)d_in[19];
    const float* g2   = (const float*)d_in[20];
    const float* gs   = (const float*)d_in[21];
    const float* be1  = (const float*)d_in[22];
    const float* be2  = (const float*)d_in[23];
    const float* bes  = (const float*)d_in[24];

    float* ws = (float*)d_ws;
    float* out = (float*)d_out;

    // NC=128 layout needs 33.8 MB of ws; fall back to NC=64 (20.7 MB) if short.
    const size_t xdbl_f = (size_t)3 * B_ * L_ * K_;          // 1,867,776
    const size_t need128 = (xdbl_f + (size_t)3*B_*128*D_ + (size_t)4*B_*128*D_*N_) * 4;

    proj_kernel<<<dim3(768), dim3(512), 0, stream>>>(xr, xsr, xe, xse, Wx1, Wx2, Wxs, ws);

    if (ws_size >= need128){
        constexpr int NCt = 128;
        float* xdbl = ws;
        float* dsum = xdbl + xdbl_f;
        float* Sbuf = dsum + (size_t)3 * B_ * NCt * D_;
        passA_kernel<NCt><<<dim3(3 * B_ * NCt), dim3(192), 0, stream>>>(xdbl, xr, xe,
            Wdt1, Wdt2, Wdts, bdt1, bdt2, bdts, Alog1, Alog2, Alogs, Sbuf, dsum);
        combine_kernel<NCt><<<dim3(192), dim3(256), 0, stream>>>(Sbuf, dsum, Alog1, Alog2, Alogs);
        passC_kernel<NCt><<<dim3(3 * B_ * NCt), dim3(192), 0, stream>>>(xdbl, xr, xe,
            Wdt1, Wdt2, Wdts, bdt1, bdt2, bdts, Alog1, Alog2, Alogs,
            Dp1, Dp2, Dps, Sbuf, out);
    } else {
        constexpr int NCt = 64;
        float* xdbl = ws;
        float* dsum = xdbl + xdbl_f;
        float* Sbuf = dsum + (size_t)3 * B_ * NCt * D_;
        passA_kernel<NCt><<<dim3(3 * B_ * NCt), dim3(192), 0, stream>>>(xdbl, xr, xe,
            Wdt1, Wdt2, Wdts, bdt1, bdt2, bdts, Alog1, Alog2, Alogs, Sbuf, dsum);
        combine_kernel<NCt><<<dim3(192), dim3(256), 0, stream>>>(Sbuf, dsum, Alog1, Alog2, Alogs);
        passC_kernel<NCt><<<dim3(3 * B_ * NCt), dim3(192), 0, stream>>>(xdbl, xr, xe,
            Wdt1, Wdt2, Wdts, bdt1, bdt2, bdts, Alog1, Alog2, Alogs,
            Dp1, Dp2, Dps, Sbuf, out);
    }

    ln_kernel<<<dim3(16384), dim3(256), 0, stream>>>(out, g1, be1, g2, be2, gs, bes);
}

// Round 6
// 358.873 us; speedup vs baseline: 1.8135x; 1.0257x over previous
//
#include <hip/hip_runtime.h>

#define B_ 4
#define L_ 4096
#define D_ 192
#define N_ 16
#define K_ 38
#define BLD (B_*L_*D_) // 3145728
#define LOG2E 1.44269504088896f

__device__ __forceinline__ float fexp2(float x){ return __builtin_amdgcn_exp2f(x); }

__device__ __forceinline__ float softplus_f(float z){
    // stable: max(z,0) + log(1+exp(-|z|))
    return fmaxf(z, 0.f) + __logf(1.f + __expf(-fabsf(z)));
}

// ---------------- P1: x_dbl[branch][b][l][38] (fp32 in ws) ----------------
// Block 512 = 8 waves; W staged in LDS (29 KB) -> ds_read broadcast, no VMEM.
// wave w: cols [w*5, w*5+5) (wave 7: 3 cols); lane: 2 rows (tile*128+lane, +64).
// Grid 384 blocks = 12 waves/CU. Inner loop: 2 global float4 + 5 LDS b128 + 40 FMA.
__global__ __launch_bounds__(512) void proj_kernel(
    const float* __restrict__ xr,  const float* __restrict__ xsr,
    const float* __restrict__ xe,  const float* __restrict__ xse,
    const float* __restrict__ Wx1, const float* __restrict__ Wx2,
    const float* __restrict__ Wxs, float* __restrict__ xdbl)
{
    __shared__ float4 Wl[K_ * 48];            // 38*48 float4 = 29184 B

    int branch = blockIdx.x / 128;            // 0..2, block-uniform
    int tile   = blockIdx.x - branch * 128;   // 0..127
    int tid  = threadIdx.x;
    int lane = tid & 63;
    int wv   = tid >> 6;                      // 0..7
    int row0 = tile * 128 + lane;             // 0..16383
    int row1 = row0 + 64;

    const float* W = (branch == 0 ? Wx1 : branch == 1 ? Wx2 : Wxs);
    const float4* Wg = (const float4*)W;
    #pragma unroll
    for (int i = 0; i < 4; i++){
        int idx = tid + i * 512;
        if (idx < K_ * 48) Wl[idx] = Wg[idx];
    }
    __syncthreads();

    int c0 = wv * 5;
    int ncols = (c0 + 5 <= K_) ? 5 : (K_ - c0);   // waves 0-6: 5, wave 7: 3

    const float4 *xa0, *xa1, *xb0 = nullptr, *xb1 = nullptr;
    if (branch == 0){
        xa0 = (const float4*)(xr + (size_t)row0 * D_);
        xa1 = (const float4*)(xr + (size_t)row1 * D_);
    } else if (branch == 1){
        xa0 = (const float4*)(xe + (size_t)row0 * D_);
        xa1 = (const float4*)(xe + (size_t)row1 * D_);
    } else {
        xa0 = (const float4*)(xsr + (size_t)row0 * D_);
        xa1 = (const float4*)(xsr + (size_t)row1 * D_);
        xb0 = (const float4*)(xse + (size_t)row0 * D_);
        xb1 = (const float4*)(xse + (size_t)row1 * D_);
    }

    float acc0[5], acc1[5];
    #pragma unroll
    for (int j = 0; j < 5; j++){ acc0[j] = 0.f; acc1[j] = 0.f; }

    #pragma unroll 4
    for (int kq = 0; kq < 48; kq++){
        float4 xv0 = xa0[kq];
        float4 xv1 = xa1[kq];
        if (branch == 2){
            float4 t0 = xb0[kq], t1 = xb1[kq];
            xv0.x += t0.x; xv0.y += t0.y; xv0.z += t0.z; xv0.w += t0.w;
            xv1.x += t1.x; xv1.y += t1.y; xv1.z += t1.z; xv1.w += t1.w;
        }
        #pragma unroll
        for (int j = 0; j < 5; j++){
            float4 wv4 = Wl[(c0 + j) * 48 + kq];    // LDS broadcast (uniform in wave)
            acc0[j] = fmaf(xv0.x, wv4.x, fmaf(xv0.y, wv4.y,
                      fmaf(xv0.z, wv4.z, fmaf(xv0.w, wv4.w, acc0[j]))));
            acc1[j] = fmaf(xv1.x, wv4.x, fmaf(xv1.y, wv4.y,
                      fmaf(xv1.z, wv4.z, fmaf(xv1.w, wv4.w, acc1[j]))));
        }
    }
    int gr0 = branch * (B_ * L_) + row0;
    int gr1 = gr0 + 64;
    float* o0 = xdbl + (size_t)gr0 * K_ + c0;
    float* o1 = xdbl + (size_t)gr1 * K_ + c0;
    #pragma unroll
    for (int j = 0; j < 5; j++)
        if (j < ncols){ o0[j] = acc0[j]; o1[j] = acc1[j]; }
}

// ---------------- Pass A: per-chunk local states S + delta-sums ----------------
// job 0: (delta,B from branch0, u=x_rgb)  -> inst 0
// job 1: (branch1, u=x_e)                 -> inst 1
// job 2: (branch2, u=x_rgb and x_e)       -> inst 2,3 (shared dA)
// S layout: [inst][b][c][d][16] fp32 ; dsum: [branch][b][c][d]
template<int NCt>
__global__ __launch_bounds__(192) void passA_kernel(
    const float* __restrict__ xdbl,
    const float* __restrict__ xr, const float* __restrict__ xe,
    const float* __restrict__ Wdt1, const float* __restrict__ Wdt2, const float* __restrict__ Wdts,
    const float* __restrict__ bdt1, const float* __restrict__ bdt2, const float* __restrict__ bdts,
    const float* __restrict__ Alog1, const float* __restrict__ Alog2, const float* __restrict__ Alogs,
    float* __restrict__ Sbuf, float* __restrict__ dsum)
{
    constexpr int CHt = L_ / NCt;
    int blk = blockIdx.x;               // 0..3*B_*NCt-1
    int job = blk / (B_ * NCt);
    int rem = blk - job * (B_ * NCt);
    int b = rem / NCt;
    int c = rem - b * NCt;
    int d = threadIdx.x;
    const bool shared = (job == 2);

    const float* Wdt  = job == 0 ? Wdt1  : job == 1 ? Wdt2  : Wdts;
    const float* bdtp = job == 0 ? bdt1  : job == 1 ? bdt2  : bdts;
    const float* Alog = job == 0 ? Alog1 : job == 1 ? Alog2 : Alogs;

    float w[6];
    #pragma unroll
    for (int r = 0; r < 6; r++) w[r] = Wdt[d * 6 + r];
    float bd = bdtp[d];
    float A2[N_];
    #pragma unroll
    for (int n = 0; n < N_; n++) A2[n] = -__expf(Alog[d * N_ + n]) * LOG2E;

    float h[N_], h2[N_];
    #pragma unroll
    for (int n = 0; n < N_; n++){ h[n] = 0.f; h2[n] = 0.f; }
    float ds = 0.f;

    const float* u1 = (job == 1) ? xe : xr;
    const float* row = xdbl + ((size_t)(job * B_ + b) * L_ + (size_t)c * CHt) * K_;
    size_t uoff = ((size_t)b * L_ + (size_t)c * CHt) * D_ + d;

    // software pipeline: one-step lookahead (row over-read past chunk end
    // lands in dsum region of ws -- valid memory, values unused)
    float cur[22];
    #pragma unroll
    for (int i = 0; i < 22; i++) cur[i] = row[i];
    float uv  = u1[uoff];
    float uv2 = shared ? xe[uoff] : 0.f;

    for (int s = 0; s < CHt; s++){
        float nxt[22];
        #pragma unroll
        for (int i = 0; i < 22; i++) nxt[i] = row[K_ + i];
        size_t uoff_n = uoff + (s + 1 < CHt ? (size_t)D_ : 0);
        float uv_n  = u1[uoff_n];
        float uv2_n = shared ? xe[uoff_n] : 0.f;

        float z = bd;
        #pragma unroll
        for (int r = 0; r < 6; r++) z = fmaf(cur[r], w[r], z);
        float delta = softplus_f(z);
        ds += delta;
        float du  = delta * uv;
        float du2 = delta * uv2;
        #pragma unroll
        for (int n = 0; n < N_; n++){
            float dA = fexp2(delta * A2[n]);
            float bn = cur[6 + n];
            h[n] = fmaf(dA, h[n], du * bn);
            if (shared) h2[n] = fmaf(dA, h2[n], du2 * bn);
        }
        row += K_;
        #pragma unroll
        for (int i = 0; i < 22; i++) cur[i] = nxt[i];
        uv = uv_n; uv2 = uv2_n; uoff = uoff_n;
    }

    int inst = shared ? 2 : job;
    size_t sidx = ((((size_t)inst * B_ + b) * NCt + c) * D_ + d) * N_;
    #pragma unroll
    for (int n = 0; n < N_; n += 4)
        *(float4*)(Sbuf + sidx + n) = make_float4(h[n], h[n+1], h[n+2], h[n+3]);
    if (shared){
        size_t sidx2 = ((((size_t)3 * B_ + b) * NCt + c) * D_ + d) * N_;
        #pragma unroll
        for (int n = 0; n < N_; n += 4)
            *(float4*)(Sbuf + sidx2 + n) = make_float4(h2[n], h2[n+1], h2[n+2], h2[n+3]);
    }
    dsum[((size_t)(job * B_ + b) * NCt + c) * D_ + d] = ds;
}

// ---------------- Combiner: thread per (inst,b,d,n); sequential over chunks.
// Converts Sbuf IN PLACE from per-chunk local end-states to chunk START states.
template<int NCt>
__global__ __launch_bounds__(256) void combine_kernel(
    float* __restrict__ Sbuf, const float* __restrict__ dsum,
    const float* __restrict__ Alog1, const float* __restrict__ Alog2, const float* __restrict__ Alogs)
{
    int tid = blockIdx.x * 256 + threadIdx.x;     // 0..49151 (grid 192)
    int inst = tid / (B_ * D_ * N_);              // uniform per block
    int rem  = tid - inst * (B_ * D_ * N_);
    int b  = rem / (D_ * N_);
    int dn = rem - b * (D_ * N_);
    int d = dn >> 4;
    int n = dn & 15;
    int branch = inst < 2 ? inst : 2;
    const float* Alog = inst == 0 ? Alog1 : inst == 1 ? Alog2 : Alogs;
    float A2 = -__expf(Alog[d * N_ + n]) * LOG2E;

    float h = 0.f;
    size_t base  = (((size_t)inst * B_ + b) * NCt) * (D_ * N_) + dn;   // + c*D_*N_
    size_t dbase = (((size_t)branch * B_ + b) * NCt) * D_ + d;         // + c*D_
    for (int c = 0; c < NCt; c++){
        size_t idx = base + (size_t)c * (D_ * N_);
        float S = Sbuf[idx];
        Sbuf[idx] = h;
        float dd = dsum[dbase + (size_t)c * D_];
        h = fmaf(fexp2(A2 * dd), h, S);
    }
}

// ---------------- Pass C: full scan with h_start, y = sum h*C + D*u ----------------
// output order: [y_rgb][y_sh_rgb][y_e][y_sh_e]
template<int NCt>
__global__ __launch_bounds__(192) void passC_kernel(
    const float* __restrict__ xdbl,
    const float* __restrict__ xr, const float* __restrict__ xe,
    const float* __restrict__ Wdt1, const float* __restrict__ Wdt2, const float* __restrict__ Wdts,
    const float* __restrict__ bdt1, const float* __restrict__ bdt2, const float* __restrict__ bdts,
    const float* __restrict__ Alog1, const float* __restrict__ Alog2, const float* __restrict__ Alogs,
    const float* __restrict__ Dp1, const float* __restrict__ Dp2, const float* __restrict__ Dps,
    const float* __restrict__ hstart,
    float* __restrict__ out)
{
    constexpr int CHt = L_ / NCt;
    int blk = blockIdx.x;
    int job = blk / (B_ * NCt);
    int rem = blk - job * (B_ * NCt);
    int b = rem / NCt;
    int c = rem - b * NCt;
    int d = threadIdx.x;
    const bool shared = (job == 2);

    const float* Wdt  = job == 0 ? Wdt1  : job == 1 ? Wdt2  : Wdts;
    const float* bdtp = job == 0 ? bdt1  : job == 1 ? bdt2  : bdts;
    const float* Alog = job == 0 ? Alog1 : job == 1 ? Alog2 : Alogs;
    float Dv = (job == 0 ? Dp1 : job == 1 ? Dp2 : Dps)[d];

    float w[6];
    #pragma unroll
    for (int r = 0; r < 6; r++) w[r] = Wdt[d * 6 + r];
    float bd = bdtp[d];
    float A2[N_];
    #pragma unroll
    for (int n = 0; n < N_; n++) A2[n] = -__expf(Alog[d * N_ + n]) * LOG2E;

    int inst = shared ? 2 : job;
    size_t hidx = ((((size_t)inst * B_ + b) * NCt + c) * D_ + d) * N_;
    float h[N_], h2[N_];
    #pragma unroll
    for (int n = 0; n < N_; n++) h[n] = hstart[hidx + n];
    if (shared){
        size_t hidx2 = ((((size_t)3 * B_ + b) * NCt + c) * D_ + d) * N_;
        #pragma unroll
        for (int n = 0; n < N_; n++) h2[n] = hstart[hidx2 + n];
    } else {
        #pragma unroll
        for (int n = 0; n < N_; n++) h2[n] = 0.f;
    }

    // C comes from the cross branch for jobs 0/1
    int cbranch = job == 0 ? 1 : job == 1 ? 0 : 2;
    const float* row  = xdbl + ((size_t)(job * B_ + b) * L_ + (size_t)c * CHt) * K_;
    const float* crow = xdbl + ((size_t)(cbranch * B_ + b) * L_ + (size_t)c * CHt) * K_ + 22;
    size_t uoff = ((size_t)b * L_ + (size_t)c * CHt) * D_ + d;
    const float* u1 = (job == 1) ? xe : xr;
    size_t obase1 = job == 0 ? 0 : job == 1 ? (size_t)2 * BLD : (size_t)1 * BLD;

    float cur[22], curC[N_];
    #pragma unroll
    for (int i = 0; i < 22; i++) cur[i] = row[i];
    #pragma unroll
    for (int n = 0; n < N_; n++) curC[n] = crow[n];
    float uv  = u1[uoff];
    float uv2 = shared ? xe[uoff] : 0.f;

    for (int s = 0; s < CHt; s++){
        float nxt[22], nxtC[N_];
        #pragma unroll
        for (int i = 0; i < 22; i++) nxt[i] = row[K_ + i];
        #pragma unroll
        for (int n = 0; n < N_; n++) nxtC[n] = crow[K_ + n];
        size_t uoff_n = uoff + (s + 1 < CHt ? (size_t)D_ : 0);
        float uv_n  = u1[uoff_n];
        float uv2_n = shared ? xe[uoff_n] : 0.f;

        float z = bd;
        #pragma unroll
        for (int r = 0; r < 6; r++) z = fmaf(cur[r], w[r], z);
        float delta = softplus_f(z);
        float du  = delta * uv;
        float du2 = delta * uv2;
        float y = 0.f, y2 = 0.f;
        #pragma unroll
        for (int n = 0; n < N_; n++){
            float dA = fexp2(delta * A2[n]);
            float bn = cur[6 + n];
            float cn = curC[n];
            h[n] = fmaf(dA, h[n], du * bn);
            y = fmaf(h[n], cn, y);
            if (shared){
                h2[n] = fmaf(dA, h2[n], du2 * bn);
                y2 = fmaf(h2[n], cn, y2);
            }
        }
        out[obase1 + uoff] = fmaf(Dv, uv, y);
        if (shared) out[(size_t)3 * BLD + uoff] = fmaf(Dv, uv2, y2);

        row += K_; crow += K_;
        #pragma unroll
        for (int i = 0; i < 22; i++) cur[i] = nxt[i];
        #pragma unroll
        for (int n = 0; n < N_; n++) curC[n] = nxtC[n];
        uv = uv_n; uv2 = uv2_n; uoff = uoff_n;
    }
}

// ---------------- LayerNorm in place on d_out (4 slots x [B][L][192]) ----------------
__global__ __launch_bounds__(256) void ln_kernel(
    float* __restrict__ out,
    const float* __restrict__ g1, const float* __restrict__ be1,
    const float* __restrict__ g2, const float* __restrict__ be2,
    const float* __restrict__ gs, const float* __restrict__ bes)
{
    int wave = threadIdx.x >> 6;
    int lane = threadIdx.x & 63;
    int rowg = blockIdx.x * 4 + wave;          // 0..65535
    int slot = rowg >> 14;                     // /(B_*L_)
    size_t base = (size_t)rowg * D_;
    const float* g  = slot == 0 ? g1  : slot == 2 ? g2  : gs;
    const float* be = slot == 0 ? be1 : slot == 2 ? be2 : bes;
    float x0 = out[base + lane];
    float x1 = out[base + lane + 64];
    float x2 = out[base + lane + 128];
    float s = x0 + x1 + x2;
    float q = x0*x0 + x1*x1 + x2*x2;
    #pragma unroll
    for (int o = 32; o > 0; o >>= 1){
        s += __shfl_xor(s, o);
        q += __shfl_xor(q, o);
    }
    float mean = s * (1.f / 192.f);
    float var  = q * (1.f / 192.f) - mean * mean;
    float rs = rsqrtf(var + 1e-5f);
    out[base + lane]       = (x0 - mean) * rs * g[lane]       + be[lane];
    out[base + lane + 64]  = (x1 - mean) * rs * g[lane + 64]  + be[lane + 64];
    out[base + lane + 128] = (x2 - mean) * rs * g[lane + 128] + be[lane + 128];
}

extern "C" void kernel_launch(void* const* d_in, const int* in_sizes, int n_in,
                              void* d_out, int out_size, void* d_ws, size_t ws_size,
                              hipStream_t stream)
{
    const float* xr   = (const float*)d_in[0];
    const float* xsr  = (const float*)d_in[1];
    const float* xe   = (const float*)d_in[2];
    const float* xse  = (const float*)d_in[3];
    const float* Wx1  = (const float*)d_in[4];
    const float* Wx2  = (const float*)d_in[5];
    const float* Wxs  = (const float*)d_in[6];
    const float* Wdt1 = (const float*)d_in[7];
    const float* Wdt2 = (const float*)d_in[8];
    const float* Wdts = (const float*)d_in[9];
    const float* bdt1 = (const float*)d_in[10];
    const float* bdt2 = (const float*)d_in[11];
    const float* bdts = (const float*)d_in[12];
    const float* Alog1= (const float*)d_in[13];
    const float* Alog2= (const float*)d_in[14];
    const float* Alogs= (const float*)d_in[15];
    const float* Dp1  = (const float*)d_in[16];
    const float* Dp2  = (const float*)d_in[17];
    const float* Dps  = (const float*)d_in[18];
    // setup_inputs() dict order: g1, g2, gs THEN be1, be2, bes
    const float* g1   = (const float*)d_in[19];
    const float* g2   = (const float*)d_in[20];
    const float* gs   = (const float*)d_in[21];
    const float* be1  = (const float*)d_in[22];
    const float* be2  = (const float*)d_in[23];
    const float* bes  = (const float*)d_in[24];

    float* ws = (float*)d_ws;
    float* out = (float*)d_out;

    // NC=128 layout needs 33.8 MB of ws; fall back to NC=64 (20.7 MB) if short.
    const size_t xdbl_f = (size_t)3 * B_ * L_ * K_;          // 1,867,776
    const size_t need128 = (xdbl_f + (size_t)3*B_*128*D_ + (size_t)4*B_*128*D_*N_) * 4;

    proj_kernel<<<dim3(384), dim3(512), 0, stream>>>(xr, xsr, xe, xse, Wx1, Wx2, Wxs, ws);

    if (ws_size >= need128){
        constexpr int NCt = 128;
        float* xdbl = ws;
        float* dsum = xdbl + xdbl_f;
        float* Sbuf = dsum + (size_t)3 * B_ * NCt * D_;
        passA_kernel<NCt><<<dim3(3 * B_ * NCt), dim3(192), 0, stream>>>(xdbl, xr, xe,
            Wdt1, Wdt2, Wdts, bdt1, bdt2, bdts, Alog1, Alog2, Alogs, Sbuf, dsum);
        combine_kernel<NCt><<<dim3(192), dim3(256), 0, stream>>>(Sbuf, dsum, Alog1, Alog2, Alogs);
        passC_kernel<NCt><<<dim3(3 * B_ * NCt), dim3(192), 0, stream>>>(xdbl, xr, xe,
            Wdt1, Wdt2, Wdts, bdt1, bdt2, bdts, Alog1, Alog2, Alogs,
            Dp1, Dp2, Dps, Sbuf, out);
    } else {
        constexpr int NCt = 64;
        float* xdbl = ws;
        float* dsum = xdbl + xdbl_f;
        float* Sbuf = dsum + (size_t)3 * B_ * NCt * D_;
        passA_kernel<NCt><<<dim3(3 * B_ * NCt), dim3(192), 0, stream>>>(xdbl, xr, xe,
            Wdt1, Wdt2, Wdts, bdt1, bdt2, bdts, Alog1, Alog2, Alogs, Sbuf, dsum);
        combine_kernel<NCt><<<dim3(192), dim3(256), 0, stream>>>(Sbuf, dsum, Alog1, Alog2, Alogs);
        passC_kernel<NCt><<<dim3(3 * B_ * NCt), dim3(192), 0, stream>>>(xdbl, xr, xe,
            Wdt1, Wdt2, Wdts, bdt1, bdt2, bdts, Alog1, Alog2, Alogs,
            Dp1, Dp2, Dps, Sbuf, out);
    }

    ln_kernel<<<dim3(16384), dim3(256), 0, stream>>>(out, g1, be1, g2, be2, gs, bes);
}

// Round 7
// 297.485 us; speedup vs baseline: 2.1877x; 1.2064x over previous
//
#include <hip/hip_runtime.h>

#define B_ 4
#define L_ 4096
#define D_ 192
#define N_ 16
#define K_ 38
#define BLD (B_*L_*D_) // 3145728
#define LOG2E 1.44269504088896f

__device__ __forceinline__ float fexp2(float x){ return __builtin_amdgcn_exp2f(x); }

__device__ __forceinline__ float softplus_f(float z){
    // stable: max(z,0) + log(1+exp(-|z|))
    return fmaxf(z, 0.f) + __logf(1.f + __expf(-fabsf(z)));
}

// ---------------- P1: x_dbl[branch][b][l][38] (fp32 in ws) ----------------
// Block 256 thr = 4 waves, 64 rows. x row-tile staged to LDS *transposed* with
// rotate swizzle (coalesced global reads; conflict-free ds_read_b128 on the
// compute side). W (29 KB) in LDS, broadcast reads. k staged in 2 phases of
// 24 float4-quads -> LDS 53 KB -> 3 blocks/CU; grid 768 fully resident.
// Hot loop: 1 ds_read_b128 + 10 LDS broadcasts + 40 FMAs per quad. No global.
__global__ __launch_bounds__(256) void proj_kernel(
    const float* __restrict__ xr,  const float* __restrict__ xsr,
    const float* __restrict__ xe,  const float* __restrict__ xse,
    const float* __restrict__ Wx1, const float* __restrict__ Wx2,
    const float* __restrict__ Wxs, float* __restrict__ xdbl)
{
    __shared__ float4 Wl[K_ * 48];        // 38*48*16 = 29184 B
    __shared__ float4 xs[24 * 64];        // 24576 B

    int branch = blockIdx.x >> 8;         // 0..2, block-uniform
    int tile   = blockIdx.x & 255;        // 0..255 (64-row tiles)
    int tid  = threadIdx.x;
    int lane = tid & 63;
    int wv   = tid >> 6;                  // 0..3

    const float* W = (branch == 0 ? Wx1 : branch == 1 ? Wx2 : Wxs);
    const float4* Wg = (const float4*)W;
    #pragma unroll
    for (int i = 0; i < 8; i++){
        int idx = tid + i * 256;
        if (idx < K_ * 48) Wl[idx] = Wg[idx];
    }

    const float* xA;
    const float* xB = nullptr;
    if (branch == 0)      xA = xr;
    else if (branch == 1) xA = xe;
    else { xA = xsr; xB = xse; }

    int c0 = wv * 10;                     // waves 0-2: 10 cols, wave 3: 8
    int ncols = (wv < 3) ? 10 : 8;

    float acc[10];
    #pragma unroll
    for (int j = 0; j < 10; j++) acc[j] = 0.f;

    #pragma unroll
    for (int p = 0; p < 2; p++){
        __syncthreads();                  // first pass also covers W staging
        // stage 64 rows x 24 quads, coalesced global (k-fastest), swizzled LDS
        #pragma unroll
        for (int i = 0; i < 6; i++){
            int f4 = i * 256 + tid;       // 0..1535
            int r  = f4 / 24;
            int kl = f4 - r * 24;
            const float4* src = (const float4*)(xA + (size_t)(tile * 64 + r) * D_);
            float4 v = src[p * 24 + kl];
            if (branch == 2){
                const float4* srcb = (const float4*)(xB + (size_t)(tile * 64 + r) * D_);
                float4 t = srcb[p * 24 + kl];
                v.x += t.x; v.y += t.y; v.z += t.z; v.w += t.w;
            }
            xs[kl * 64 + ((r + kl) & 63)] = v;
        }
        __syncthreads();
        // compute
        #pragma unroll 4
        for (int kl = 0; kl < 24; kl++){
            float4 xv = xs[kl * 64 + ((lane + kl) & 63)];   // conflict-free b128
            int k4 = p * 24 + kl;
            #pragma unroll
            for (int j = 0; j < 10; j++){
                if (j < ncols){
                    float4 wv4 = Wl[(c0 + j) * 48 + k4];    // broadcast
                    acc[j] = fmaf(xv.x, wv4.x, fmaf(xv.y, wv4.y,
                             fmaf(xv.z, wv4.z, fmaf(xv.w, wv4.w, acc[j]))));
                }
            }
        }
    }

    int gr = branch * (B_ * L_) + tile * 64 + lane;
    float* o = xdbl + (size_t)gr * K_ + c0;
    #pragma unroll
    for (int j = 0; j < 10; j++)
        if (j < ncols) o[j] = acc[j];
}

// ---------------- Pass A: per-chunk local states S + delta-sums ----------------
// job 0: (delta,B from branch0, u=x_rgb)  -> inst 0
// job 1: (branch1, u=x_e)                 -> inst 1
// job 2: (branch2, u=x_rgb and x_e)       -> inst 2,3 (shared dA)
// S layout: [inst][b][c][d][16] fp32 ; dsum: [branch][b][c][d]
template<int NCt>
__global__ __launch_bounds__(192) void passA_kernel(
    const float* __restrict__ xdbl,
    const float* __restrict__ xr, const float* __restrict__ xe,
    const float* __restrict__ Wdt1, const float* __restrict__ Wdt2, const float* __restrict__ Wdts,
    const float* __restrict__ bdt1, const float* __restrict__ bdt2, const float* __restrict__ bdts,
    const float* __restrict__ Alog1, const float* __restrict__ Alog2, const float* __restrict__ Alogs,
    float* __restrict__ Sbuf, float* __restrict__ dsum)
{
    constexpr int CHt = L_ / NCt;
    int blk = blockIdx.x;               // 0..3*B_*NCt-1
    int job = blk / (B_ * NCt);
    int rem = blk - job * (B_ * NCt);
    int b = rem / NCt;
    int c = rem - b * NCt;
    int d = threadIdx.x;
    const bool shared = (job == 2);

    const float* Wdt  = job == 0 ? Wdt1  : job == 1 ? Wdt2  : Wdts;
    const float* bdtp = job == 0 ? bdt1  : job == 1 ? bdt2  : bdts;
    const float* Alog = job == 0 ? Alog1 : job == 1 ? Alog2 : Alogs;

    float w[6];
    #pragma unroll
    for (int r = 0; r < 6; r++) w[r] = Wdt[d * 6 + r];
    float bd = bdtp[d];
    float A2[N_];
    #pragma unroll
    for (int n = 0; n < N_; n++) A2[n] = -__expf(Alog[d * N_ + n]) * LOG2E;

    float h[N_], h2[N_];
    #pragma unroll
    for (int n = 0; n < N_; n++){ h[n] = 0.f; h2[n] = 0.f; }
    float ds = 0.f;

    const float* u1 = (job == 1) ? xe : xr;
    const float* row = xdbl + ((size_t)(job * B_ + b) * L_ + (size_t)c * CHt) * K_;
    size_t uoff = ((size_t)b * L_ + (size_t)c * CHt) * D_ + d;

    // software pipeline: one-step lookahead (row over-read past chunk end
    // lands in dsum region of ws -- valid memory, values unused)
    float cur[22];
    #pragma unroll
    for (int i = 0; i < 22; i++) cur[i] = row[i];
    float uv  = u1[uoff];
    float uv2 = shared ? xe[uoff] : 0.f;

    for (int s = 0; s < CHt; s++){
        float nxt[22];
        #pragma unroll
        for (int i = 0; i < 22; i++) nxt[i] = row[K_ + i];
        size_t uoff_n = uoff + (s + 1 < CHt ? (size_t)D_ : 0);
        float uv_n  = u1[uoff_n];
        float uv2_n = shared ? xe[uoff_n] : 0.f;

        float z = bd;
        #pragma unroll
        for (int r = 0; r < 6; r++) z = fmaf(cur[r], w[r], z);
        float delta = softplus_f(z);
        ds += delta;
        float du  = delta * uv;
        float du2 = delta * uv2;
        #pragma unroll
        for (int n = 0; n < N_; n++){
            float dA = fexp2(delta * A2[n]);
            float bn = cur[6 + n];
            h[n] = fmaf(dA, h[n], du * bn);
            if (shared) h2[n] = fmaf(dA, h2[n], du2 * bn);
        }
        row += K_;
        #pragma unroll
        for (int i = 0; i < 22; i++) cur[i] = nxt[i];
        uv = uv_n; uv2 = uv2_n; uoff = uoff_n;
    }

    int inst = shared ? 2 : job;
    size_t sidx = ((((size_t)inst * B_ + b) * NCt + c) * D_ + d) * N_;
    #pragma unroll
    for (int n = 0; n < N_; n += 4)
        *(float4*)(Sbuf + sidx + n) = make_float4(h[n], h[n+1], h[n+2], h[n+3]);
    if (shared){
        size_t sidx2 = ((((size_t)3 * B_ + b) * NCt + c) * D_ + d) * N_;
        #pragma unroll
        for (int n = 0; n < N_; n += 4)
            *(float4*)(Sbuf + sidx2 + n) = make_float4(h2[n], h2[n+1], h2[n+2], h2[n+3]);
    }
    dsum[((size_t)(job * B_ + b) * NCt + c) * D_ + d] = ds;
}

// ---------------- Combiner: thread per (inst,b,d,n); sequential over chunks.
// Converts Sbuf IN PLACE from per-chunk local end-states to chunk START states.
template<int NCt>
__global__ __launch_bounds__(256) void combine_kernel(
    float* __restrict__ Sbuf, const float* __restrict__ dsum,
    const float* __restrict__ Alog1, const float* __restrict__ Alog2, const float* __restrict__ Alogs)
{
    int tid = blockIdx.x * 256 + threadIdx.x;     // 0..49151 (grid 192)
    int inst = tid / (B_ * D_ * N_);              // uniform per block
    int rem  = tid - inst * (B_ * D_ * N_);
    int b  = rem / (D_ * N_);
    int dn = rem - b * (D_ * N_);
    int d = dn >> 4;
    int n = dn & 15;
    int branch = inst < 2 ? inst : 2;
    const float* Alog = inst == 0 ? Alog1 : inst == 1 ? Alog2 : Alogs;
    float A2 = -__expf(Alog[d * N_ + n]) * LOG2E;

    float h = 0.f;
    size_t base  = (((size_t)inst * B_ + b) * NCt) * (D_ * N_) + dn;   // + c*D_*N_
    size_t dbase = (((size_t)branch * B_ + b) * NCt) * D_ + d;         // + c*D_
    for (int c = 0; c < NCt; c++){
        size_t idx = base + (size_t)c * (D_ * N_);
        float S = Sbuf[idx];
        Sbuf[idx] = h;
        float dd = dsum[dbase + (size_t)c * D_];
        h = fmaf(fexp2(A2 * dd), h, S);
    }
}

// ---------------- Pass C: full scan with h_start, y = sum h*C + D*u ----------------
// output order: [y_rgb][y_sh_rgb][y_e][y_sh_e]
template<int NCt>
__global__ __launch_bounds__(192) void passC_kernel(
    const float* __restrict__ xdbl,
    const float* __restrict__ xr, const float* __restrict__ xe,
    const float* __restrict__ Wdt1, const float* __restrict__ Wdt2, const float* __restrict__ Wdts,
    const float* __restrict__ bdt1, const float* __restrict__ bdt2, const float* __restrict__ bdts,
    const float* __restrict__ Alog1, const float* __restrict__ Alog2, const float* __restrict__ Alogs,
    const float* __restrict__ Dp1, const float* __restrict__ Dp2, const float* __restrict__ Dps,
    const float* __restrict__ hstart,
    float* __restrict__ out)
{
    constexpr int CHt = L_ / NCt;
    int blk = blockIdx.x;
    int job = blk / (B_ * NCt);
    int rem = blk - job * (B_ * NCt);
    int b = rem / NCt;
    int c = rem - b * NCt;
    int d = threadIdx.x;
    const bool shared = (job == 2);

    const float* Wdt  = job == 0 ? Wdt1  : job == 1 ? Wdt2  : Wdts;
    const float* bdtp = job == 0 ? bdt1  : job == 1 ? bdt2  : bdts;
    const float* Alog = job == 0 ? Alog1 : job == 1 ? Alog2 : Alogs;
    float Dv = (job == 0 ? Dp1 : job == 1 ? Dp2 : Dps)[d];

    float w[6];
    #pragma unroll
    for (int r = 0; r < 6; r++) w[r] = Wdt[d * 6 + r];
    float bd = bdtp[d];
    float A2[N_];
    #pragma unroll
    for (int n = 0; n < N_; n++) A2[n] = -__expf(Alog[d * N_ + n]) * LOG2E;

    int inst = shared ? 2 : job;
    size_t hidx = ((((size_t)inst * B_ + b) * NCt + c) * D_ + d) * N_;
    float h[N_], h2[N_];
    #pragma unroll
    for (int n = 0; n < N_; n++) h[n] = hstart[hidx + n];
    if (shared){
        size_t hidx2 = ((((size_t)3 * B_ + b) * NCt + c) * D_ + d) * N_;
        #pragma unroll
        for (int n = 0; n < N_; n++) h2[n] = hstart[hidx2 + n];
    } else {
        #pragma unroll
        for (int n = 0; n < N_; n++) h2[n] = 0.f;
    }

    // C comes from the cross branch for jobs 0/1
    int cbranch = job == 0 ? 1 : job == 1 ? 0 : 2;
    const float* row  = xdbl + ((size_t)(job * B_ + b) * L_ + (size_t)c * CHt) * K_;
    const float* crow = xdbl + ((size_t)(cbranch * B_ + b) * L_ + (size_t)c * CHt) * K_ + 22;
    size_t uoff = ((size_t)b * L_ + (size_t)c * CHt) * D_ + d;
    const float* u1 = (job == 1) ? xe : xr;
    size_t obase1 = job == 0 ? 0 : job == 1 ? (size_t)2 * BLD : (size_t)1 * BLD;

    float cur[22], curC[N_];
    #pragma unroll
    for (int i = 0; i < 22; i++) cur[i] = row[i];
    #pragma unroll
    for (int n = 0; n < N_; n++) curC[n] = crow[n];
    float uv  = u1[uoff];
    float uv2 = shared ? xe[uoff] : 0.f;

    for (int s = 0; s < CHt; s++){
        float nxt[22], nxtC[N_];
        #pragma unroll
        for (int i = 0; i < 22; i++) nxt[i] = row[K_ + i];
        #pragma unroll
        for (int n = 0; n < N_; n++) nxtC[n] = crow[K_ + n];
        size_t uoff_n = uoff + (s + 1 < CHt ? (size_t)D_ : 0);
        float uv_n  = u1[uoff_n];
        float uv2_n = shared ? xe[uoff_n] : 0.f;

        float z = bd;
        #pragma unroll
        for (int r = 0; r < 6; r++) z = fmaf(cur[r], w[r], z);
        float delta = softplus_f(z);
        float du  = delta * uv;
        float du2 = delta * uv2;
        float y = 0.f, y2 = 0.f;
        #pragma unroll
        for (int n = 0; n < N_; n++){
            float dA = fexp2(delta * A2[n]);
            float bn = cur[6 + n];
            float cn = curC[n];
            h[n] = fmaf(dA, h[n], du * bn);
            y = fmaf(h[n], cn, y);
            if (shared){
                h2[n] = fmaf(dA, h2[n], du2 * bn);
                y2 = fmaf(h2[n], cn, y2);
            }
        }
        out[obase1 + uoff] = fmaf(Dv, uv, y);
        if (shared) out[(size_t)3 * BLD + uoff] = fmaf(Dv, uv2, y2);

        row += K_; crow += K_;
        #pragma unroll
        for (int i = 0; i < 22; i++) cur[i] = nxt[i];
        #pragma unroll
        for (int n = 0; n < N_; n++) curC[n] = nxtC[n];
        uv = uv_n; uv2 = uv2_n; uoff = uoff_n;
    }
}

// ---------------- LayerNorm in place on d_out (4 slots x [B][L][192]) ----------------
__global__ __launch_bounds__(256) void ln_kernel(
    float* __restrict__ out,
    const float* __restrict__ g1, const float* __restrict__ be1,
    const float* __restrict__ g2, const float* __restrict__ be2,
    const float* __restrict__ gs, const float* __restrict__ bes)
{
    int wave = threadIdx.x >> 6;
    int lane = threadIdx.x & 63;
    int rowg = blockIdx.x * 4 + wave;          // 0..65535
    int slot = rowg >> 14;                     // /(B_*L_)
    size_t base = (size_t)rowg * D_;
    const float* g  = slot == 0 ? g1  : slot == 2 ? g2  : gs;
    const float* be = slot == 0 ? be1 : slot == 2 ? be2 : bes;
    float x0 = out[base + lane];
    float x1 = out[base + lane + 64];
    float x2 = out[base + lane + 128];
    float s = x0 + x1 + x2;
    float q = x0*x0 + x1*x1 + x2*x2;
    #pragma unroll
    for (int o = 32; o > 0; o >>= 1){
        s += __shfl_xor(s, o);
        q += __shfl_xor(q, o);
    }
    float mean = s * (1.f / 192.f);
    float var  = q * (1.f / 192.f) - mean * mean;
    float rs = rsqrtf(var + 1e-5f);
    out[base + lane]       = (x0 - mean) * rs * g[lane]       + be[lane];
    out[base + lane + 64]  = (x1 - mean) * rs * g[lane + 64]  + be[lane + 64];
    out[base + lane + 128] = (x2 - mean) * rs * g[lane + 128] + be[lane + 128];
}

extern "C" void kernel_launch(void* const* d_in, const int* in_sizes, int n_in,
                              void* d_out, int out_size, void* d_ws, size_t ws_size,
                              hipStream_t stream)
{
    const float* xr   = (const float*)d_in[0];
    const float* xsr  = (const float*)d_in[1];
    const float* xe   = (const float*)d_in[2];
    const float* xse  = (const float*)d_in[3];
    const float* Wx1  = (const float*)d_in[4];
    const float* Wx2  = (const float*)d_in[5];
    const float* Wxs  = (const float*)d_in[6];
    const float* Wdt1 = (const float*)d_in[7];
    const float* Wdt2 = (const float*)d_in[8];
    const float* Wdts = (const float*)d_in[9];
    const float* bdt1 = (const float*)d_in[10];
    const float* bdt2 = (const float*)d_in[11];
    const float* bdts = (const float*)d_in[12];
    const float* Alog1= (const float*)d_in[13];
    const float* Alog2= (const float*)d_in[14];
    const float* Alogs= (const float*)d_in[15];
    const float* Dp1  = (const float*)d_in[16];
    const float* Dp2  = (const float*)d_in[17];
    const float* Dps  = (const float*)d_in[18];
    // setup_inputs() dict order: g1, g2, gs THEN be1, be2, bes
    const float* g1   = (const float*)d_in[19];
    const float* g2   = (const float*)d_in[20];
    const float* gs   = (const float*)d_in[21];
    const float* be1  = (const float*)d_in[22];
    const float* be2  = (const float*)d_in[23];
    const float* bes  = (const float*)d_in[24];

    float* ws = (float*)d_ws;
    float* out = (float*)d_out;

    // NC=128 layout needs 33.8 MB of ws; fall back to NC=64 (20.7 MB) if short.
    const size_t xdbl_f = (size_t)3 * B_ * L_ * K_;          // 1,867,776
    const size_t need128 = (xdbl_f + (size_t)3*B_*128*D_ + (size_t)4*B_*128*D_*N_) * 4;

    proj_kernel<<<dim3(768), dim3(256), 0, stream>>>(xr, xsr, xe, xse, Wx1, Wx2, Wxs, ws);

    if (ws_size >= need128){
        constexpr int NCt = 128;
        float* xdbl = ws;
        float* dsum = xdbl + xdbl_f;
        float* Sbuf = dsum + (size_t)3 * B_ * NCt * D_;
        passA_kernel<NCt><<<dim3(3 * B_ * NCt), dim3(192), 0, stream>>>(xdbl, xr, xe,
            Wdt1, Wdt2, Wdts, bdt1, bdt2, bdts, Alog1, Alog2, Alogs, Sbuf, dsum);
        combine_kernel<NCt><<<dim3(192), dim3(256), 0, stream>>>(Sbuf, dsum, Alog1, Alog2, Alogs);
        passC_kernel<NCt><<<dim3(3 * B_ * NCt), dim3(192), 0, stream>>>(xdbl, xr, xe,
            Wdt1, Wdt2, Wdts, bdt1, bdt2, bdts, Alog1, Alog2, Alogs,
            Dp1, Dp2, Dps, Sbuf, out);
    } else {
        constexpr int NCt = 64;
        float* xdbl = ws;
        float* dsum = xdbl + xdbl_f;
        float* Sbuf = dsum + (size_t)3 * B_ * NCt * D_;
        passA_kernel<NCt><<<dim3(3 * B_ * NCt), dim3(192), 0, stream>>>(xdbl, xr, xe,
            Wdt1, Wdt2, Wdts, bdt1, bdt2, bdts, Alog1, Alog2, Alogs, Sbuf, dsum);
        combine_kernel<NCt><<<dim3(192), dim3(256), 0, stream>>>(Sbuf, dsum, Alog1, Alog2, Alogs);
        passC_kernel<NCt><<<dim3(3 * B_ * NCt), dim3(192), 0, stream>>>(xdbl, xr, xe,
            Wdt1, Wdt2, Wdts, bdt1, bdt2, bdts, Alog1, Alog2, Alogs,
            Dp1, Dp2, Dps, Sbuf, out);
    }

    ln_kernel<<<dim3(16384), dim3(256), 0, stream>>>(out, g1, be1, g2, be2, gs, bes);
}

// Round 8
// 297.358 us; speedup vs baseline: 2.1886x; 1.0004x over previous
//
#include <hip/hip_runtime.h>

#define B_ 4
#define L_ 4096
#define D_ 192
#define N_ 16
#define K_ 38
#define BLD (B_*L_*D_) // 3145728
#define LOG2E 1.44269504088896f

__device__ __forceinline__ float fexp2(float x){ return __builtin_amdgcn_exp2f(x); }

__device__ __forceinline__ float softplus_f(float z){
    // stable: max(z,0) + log(1+exp(-|z|))
    return fmaxf(z, 0.f) + __logf(1.f + __expf(-fabsf(z)));
}

// ---------------- P1: x_dbl[branch][b][l][38] (fp32 in ws) ----------------
// Block 256 thr = 4 waves, 64 rows. x row-tile staged to LDS *transposed* with
// rotate swizzle (coalesced global reads; conflict-free ds_read_b128 on the
// compute side). W (29 KB) in LDS, broadcast reads.
__global__ __launch_bounds__(256) void proj_kernel(
    const float* __restrict__ xr,  const float* __restrict__ xsr,
    const float* __restrict__ xe,  const float* __restrict__ xse,
    const float* __restrict__ Wx1, const float* __restrict__ Wx2,
    const float* __restrict__ Wxs, float* __restrict__ xdbl)
{
    __shared__ float4 Wl[K_ * 48];        // 38*48*16 = 29184 B
    __shared__ float4 xs[24 * 64];        // 24576 B

    int branch = blockIdx.x >> 8;         // 0..2, block-uniform
    int tile   = blockIdx.x & 255;        // 0..255 (64-row tiles)
    int tid  = threadIdx.x;
    int lane = tid & 63;
    int wv   = tid >> 6;                  // 0..3

    const float* W = (branch == 0 ? Wx1 : branch == 1 ? Wx2 : Wxs);
    const float4* Wg = (const float4*)W;
    #pragma unroll
    for (int i = 0; i < 8; i++){
        int idx = tid + i * 256;
        if (idx < K_ * 48) Wl[idx] = Wg[idx];
    }

    const float* xA;
    const float* xB = nullptr;
    if (branch == 0)      xA = xr;
    else if (branch == 1) xA = xe;
    else { xA = xsr; xB = xse; }

    int c0 = wv * 10;                     // waves 0-2: 10 cols, wave 3: 8
    int ncols = (wv < 3) ? 10 : 8;

    float acc[10];
    #pragma unroll
    for (int j = 0; j < 10; j++) acc[j] = 0.f;

    #pragma unroll
    for (int p = 0; p < 2; p++){
        __syncthreads();                  // first pass also covers W staging
        #pragma unroll
        for (int i = 0; i < 6; i++){
            int f4 = i * 256 + tid;       // 0..1535
            int r  = f4 / 24;
            int kl = f4 - r * 24;
            const float4* src = (const float4*)(xA + (size_t)(tile * 64 + r) * D_);
            float4 v = src[p * 24 + kl];
            if (branch == 2){
                const float4* srcb = (const float4*)(xB + (size_t)(tile * 64 + r) * D_);
                float4 t = srcb[p * 24 + kl];
                v.x += t.x; v.y += t.y; v.z += t.z; v.w += t.w;
            }
            xs[kl * 64 + ((r + kl) & 63)] = v;
        }
        __syncthreads();
        #pragma unroll 4
        for (int kl = 0; kl < 24; kl++){
            float4 xv = xs[kl * 64 + ((lane + kl) & 63)];   // conflict-free b128
            int k4 = p * 24 + kl;
            #pragma unroll
            for (int j = 0; j < 10; j++){
                if (j < ncols){
                    float4 wv4 = Wl[(c0 + j) * 48 + k4];    // broadcast
                    acc[j] = fmaf(xv.x, wv4.x, fmaf(xv.y, wv4.y,
                             fmaf(xv.z, wv4.z, fmaf(xv.w, wv4.w, acc[j]))));
                }
            }
        }
    }

    int gr = branch * (B_ * L_) + tile * 64 + lane;
    float* o = xdbl + (size_t)gr * K_ + c0;
    #pragma unroll
    for (int j = 0; j < 10; j++)
        if (j < ncols) o[j] = acc[j];
}

// ---------------- Pass A: per-chunk local states S + delta-sums ----------------
// Heavy job (2, shared: two scans) dispatched FIRST for tail balance.
// S layout: [inst][b][c][d][16] fp32 ; dsum: [branch][b][c][d]
template<int NCt>
__global__ __launch_bounds__(192) void passA_kernel(
    const float* __restrict__ xdbl,
    const float* __restrict__ xr, const float* __restrict__ xe,
    const float* __restrict__ Wdt1, const float* __restrict__ Wdt2, const float* __restrict__ Wdts,
    const float* __restrict__ bdt1, const float* __restrict__ bdt2, const float* __restrict__ bdts,
    const float* __restrict__ Alog1, const float* __restrict__ Alog2, const float* __restrict__ Alogs,
    float* __restrict__ Sbuf, float* __restrict__ dsum)
{
    constexpr int CHt = L_ / NCt;
    int blk = blockIdx.x;               // 0..3*B_*NCt-1
    int q   = blk / (B_ * NCt);
    int job = 2 - q;                    // heavy job first
    int rem = blk - q * (B_ * NCt);
    int b = rem / NCt;
    int c = rem - b * NCt;
    int d = threadIdx.x;
    const bool shared = (job == 2);

    const float* Wdt  = job == 0 ? Wdt1  : job == 1 ? Wdt2  : Wdts;
    const float* bdtp = job == 0 ? bdt1  : job == 1 ? bdt2  : bdts;
    const float* Alog = job == 0 ? Alog1 : job == 1 ? Alog2 : Alogs;

    float w[6];
    #pragma unroll
    for (int r = 0; r < 6; r++) w[r] = Wdt[d * 6 + r];
    float bd = bdtp[d];
    float A2[N_];
    #pragma unroll
    for (int n = 0; n < N_; n++) A2[n] = -__expf(Alog[d * N_ + n]) * LOG2E;

    float h[N_], h2[N_];
    #pragma unroll
    for (int n = 0; n < N_; n++){ h[n] = 0.f; h2[n] = 0.f; }
    float ds = 0.f;

    const float* u1 = (job == 1) ? xe : xr;
    const float* row = xdbl + ((size_t)(job * B_ + b) * L_ + (size_t)c * CHt) * K_;
    size_t uoff = ((size_t)b * L_ + (size_t)c * CHt) * D_ + d;

    float cur[22];
    #pragma unroll
    for (int i = 0; i < 22; i++) cur[i] = row[i];
    float uv  = u1[uoff];
    float uv2 = shared ? xe[uoff] : 0.f;

    #pragma unroll 2
    for (int s = 0; s < CHt; s++){
        float nxt[22];
        #pragma unroll
        for (int i = 0; i < 22; i++) nxt[i] = row[K_ + i];
        size_t uoff_n = uoff + (s + 1 < CHt ? (size_t)D_ : 0);
        float uv_n  = u1[uoff_n];
        float uv2_n = shared ? xe[uoff_n] : 0.f;

        float z = bd;
        #pragma unroll
        for (int r = 0; r < 6; r++) z = fmaf(cur[r], w[r], z);
        float delta = softplus_f(z);
        ds += delta;
        float du  = delta * uv;
        float du2 = delta * uv2;
        #pragma unroll
        for (int n = 0; n < N_; n++){
            float dA = fexp2(delta * A2[n]);
            float bn = cur[6 + n];
            h[n] = fmaf(dA, h[n], du * bn);
            if (shared) h2[n] = fmaf(dA, h2[n], du2 * bn);
        }
        row += K_;
        #pragma unroll
        for (int i = 0; i < 22; i++) cur[i] = nxt[i];
        uv = uv_n; uv2 = uv2_n; uoff = uoff_n;
    }

    int inst = shared ? 2 : job;
    size_t sidx = ((((size_t)inst * B_ + b) * NCt + c) * D_ + d) * N_;
    #pragma unroll
    for (int n = 0; n < N_; n += 4)
        *(float4*)(Sbuf + sidx + n) = make_float4(h[n], h[n+1], h[n+2], h[n+3]);
    if (shared){
        size_t sidx2 = ((((size_t)3 * B_ + b) * NCt + c) * D_ + d) * N_;
        #pragma unroll
        for (int n = 0; n < N_; n += 4)
            *(float4*)(Sbuf + sidx2 + n) = make_float4(h2[n], h2[n+1], h2[n+2], h2[n+3]);
    }
    dsum[((size_t)(job * B_ + b) * NCt + c) * D_ + d] = ds;
}

// ---------------- Combiner: thread per (inst,b,d,n); sequential over chunks.
// Converts Sbuf IN PLACE from per-chunk local end-states to chunk START states.
template<int NCt>
__global__ __launch_bounds__(256) void combine_kernel(
    float* __restrict__ Sbuf, const float* __restrict__ dsum,
    const float* __restrict__ Alog1, const float* __restrict__ Alog2, const float* __restrict__ Alogs)
{
    int tid = blockIdx.x * 256 + threadIdx.x;     // 0..49151 (grid 192)
    int inst = tid / (B_ * D_ * N_);              // uniform per block
    int rem  = tid - inst * (B_ * D_ * N_);
    int b  = rem / (D_ * N_);
    int dn = rem - b * (D_ * N_);
    int d = dn >> 4;
    int n = dn & 15;
    int branch = inst < 2 ? inst : 2;
    const float* Alog = inst == 0 ? Alog1 : inst == 1 ? Alog2 : Alogs;
    float A2 = -__expf(Alog[d * N_ + n]) * LOG2E;

    float h = 0.f;
    size_t base  = (((size_t)inst * B_ + b) * NCt) * (D_ * N_) + dn;   // + c*D_*N_
    size_t dbase = (((size_t)branch * B_ + b) * NCt) * D_ + d;         // + c*D_
    for (int c = 0; c < NCt; c++){
        size_t idx = base + (size_t)c * (D_ * N_);
        float S = Sbuf[idx];
        Sbuf[idx] = h;
        float dd = dsum[dbase + (size_t)c * D_];
        h = fmaf(fexp2(A2 * dd), h, S);
    }
}

// ---------------- Pass C: scan with h_start, y = sum h*C + D*u, FUSED LayerNorm.
// Buffers 32 output rows in LDS, then per-wave shuffle-reduce LN + coalesced store.
// output order: [y_rgb][y_sh_rgb][y_e][y_sh_e]
template<int NCt>
__global__ __launch_bounds__(192) void passC_kernel(
    const float* __restrict__ xdbl,
    const float* __restrict__ xr, const float* __restrict__ xe,
    const float* __restrict__ Wdt1, const float* __restrict__ Wdt2, const float* __restrict__ Wdts,
    const float* __restrict__ bdt1, const float* __restrict__ bdt2, const float* __restrict__ bdts,
    const float* __restrict__ Alog1, const float* __restrict__ Alog2, const float* __restrict__ Alogs,
    const float* __restrict__ Dp1, const float* __restrict__ Dp2, const float* __restrict__ Dps,
    const float* __restrict__ g1, const float* __restrict__ g2, const float* __restrict__ gs,
    const float* __restrict__ be1, const float* __restrict__ be2, const float* __restrict__ bes,
    const float* __restrict__ hstart,
    float* __restrict__ out)
{
    constexpr int CHt = L_ / NCt;
    constexpr int NB  = CHt / 32;
    __shared__ float ys [32 * D_];      // 24576 B
    __shared__ float ys2[32 * D_];      // 24576 B

    int blk = blockIdx.x;
    int q   = blk / (B_ * NCt);
    int job = 2 - q;                    // heavy job first
    int rem = blk - q * (B_ * NCt);
    int b = rem / NCt;
    int c = rem - b * NCt;
    int d = threadIdx.x;
    int lane = d & 63;
    int wvi  = d >> 6;                  // 0..2
    const bool shared = (job == 2);

    const float* Wdt  = job == 0 ? Wdt1  : job == 1 ? Wdt2  : Wdts;
    const float* bdtp = job == 0 ? bdt1  : job == 1 ? bdt2  : bdts;
    const float* Alog = job == 0 ? Alog1 : job == 1 ? Alog2 : Alogs;
    float Dv = (job == 0 ? Dp1 : job == 1 ? Dp2 : Dps)[d];
    const float* gp = job == 0 ? g1  : job == 1 ? g2  : gs;
    const float* bp = job == 0 ? be1 : job == 1 ? be2 : bes;
    float gl[3], bl[3];
    #pragma unroll
    for (int i = 0; i < 3; i++){ gl[i] = gp[lane + 64*i]; bl[i] = bp[lane + 64*i]; }

    float w[6];
    #pragma unroll
    for (int r = 0; r < 6; r++) w[r] = Wdt[d * 6 + r];
    float bd = bdtp[d];
    float A2[N_];
    #pragma unroll
    for (int n = 0; n < N_; n++) A2[n] = -__expf(Alog[d * N_ + n]) * LOG2E;

    int inst = shared ? 2 : job;
    size_t hidx = ((((size_t)inst * B_ + b) * NCt + c) * D_ + d) * N_;
    float h[N_], h2[N_];
    #pragma unroll
    for (int n = 0; n < N_; n++) h[n] = hstart[hidx + n];
    if (shared){
        size_t hidx2 = ((((size_t)3 * B_ + b) * NCt + c) * D_ + d) * N_;
        #pragma unroll
        for (int n = 0; n < N_; n++) h2[n] = hstart[hidx2 + n];
    } else {
        #pragma unroll
        for (int n = 0; n < N_; n++) h2[n] = 0.f;
    }

    int cbranch = job == 0 ? 1 : job == 1 ? 0 : 2;
    const float* row  = xdbl + ((size_t)(job * B_ + b) * L_ + (size_t)c * CHt) * K_;
    const float* crow = xdbl + ((size_t)(cbranch * B_ + b) * L_ + (size_t)c * CHt) * K_ + 22;
    size_t uoff = ((size_t)b * L_ + (size_t)c * CHt) * D_ + d;
    const float* u1 = (job == 1) ? xe : xr;
    size_t obase1 = job == 0 ? 0 : job == 1 ? (size_t)2 * BLD : (size_t)1 * BLD;

    float cur[22], curC[N_];
    #pragma unroll
    for (int i = 0; i < 22; i++) cur[i] = row[i];
    #pragma unroll
    for (int n = 0; n < N_; n++) curC[n] = crow[n];
    float uv  = u1[uoff];
    float uv2 = shared ? xe[uoff] : 0.f;

    for (int batch = 0; batch < NB; batch++){
        #pragma unroll 2
        for (int t = 0; t < 32; t++){
            int s = batch * 32 + t;
            float nxt[22], nxtC[N_];
            #pragma unroll
            for (int i = 0; i < 22; i++) nxt[i] = row[K_ + i];
            #pragma unroll
            for (int n = 0; n < N_; n++) nxtC[n] = crow[K_ + n];
            size_t uoff_n = uoff + (s + 1 < CHt ? (size_t)D_ : 0);
            float uv_n  = u1[uoff_n];
            float uv2_n = shared ? xe[uoff_n] : 0.f;

            float z = bd;
            #pragma unroll
            for (int r = 0; r < 6; r++) z = fmaf(cur[r], w[r], z);
            float delta = softplus_f(z);
            float du  = delta * uv;
            float du2 = delta * uv2;
            float ya = 0.f, yb = 0.f, yc = 0.f, yd = 0.f;
            float ya2 = 0.f, yb2 = 0.f, yc2 = 0.f, yd2 = 0.f;
            #pragma unroll
            for (int n = 0; n < N_; n += 4){
                float dA0 = fexp2(delta * A2[n]);
                float dA1 = fexp2(delta * A2[n+1]);
                float dA2_ = fexp2(delta * A2[n+2]);
                float dA3 = fexp2(delta * A2[n+3]);
                h[n]   = fmaf(dA0, h[n],   du * cur[6+n]);
                h[n+1] = fmaf(dA1, h[n+1], du * cur[7+n]);
                h[n+2] = fmaf(dA2_, h[n+2], du * cur[8+n]);
                h[n+3] = fmaf(dA3, h[n+3], du * cur[9+n]);
                ya = fmaf(h[n],   curC[n],   ya);
                yb = fmaf(h[n+1], curC[n+1], yb);
                yc = fmaf(h[n+2], curC[n+2], yc);
                yd = fmaf(h[n+3], curC[n+3], yd);
                if (shared){
                    h2[n]   = fmaf(dA0, h2[n],   du2 * cur[6+n]);
                    h2[n+1] = fmaf(dA1, h2[n+1], du2 * cur[7+n]);
                    h2[n+2] = fmaf(dA2_, h2[n+2], du2 * cur[8+n]);
                    h2[n+3] = fmaf(dA3, h2[n+3], du2 * cur[9+n]);
                    ya2 = fmaf(h2[n],   curC[n],   ya2);
                    yb2 = fmaf(h2[n+1], curC[n+1], yb2);
                    yc2 = fmaf(h2[n+2], curC[n+2], yc2);
                    yd2 = fmaf(h2[n+3], curC[n+3], yd2);
                }
            }
            ys[t * D_ + d] = fmaf(Dv, uv, (ya + yb) + (yc + yd));
            if (shared) ys2[t * D_ + d] = fmaf(Dv, uv2, (ya2 + yb2) + (yc2 + yd2));

            row += K_; crow += K_;
            #pragma unroll
            for (int i = 0; i < 22; i++) cur[i] = nxt[i];
            #pragma unroll
            for (int n = 0; n < N_; n++) curC[n] = nxtC[n];
            uv = uv_n; uv2 = uv2_n; uoff = uoff_n;
        }

        // ---- fused LayerNorm flush of 32 rows ----
        __syncthreads();
        size_t lbase = (size_t)b * L_ + (size_t)c * CHt + batch * 32;
        for (int r = wvi; r < 32; r += 3){
            float x0 = ys[r * D_ + lane];
            float x1 = ys[r * D_ + lane + 64];
            float x2 = ys[r * D_ + lane + 128];
            float sm = x0 + x1 + x2;
            float qm = x0*x0 + x1*x1 + x2*x2;
            #pragma unroll
            for (int o = 32; o > 0; o >>= 1){
                sm += __shfl_xor(sm, o);
                qm += __shfl_xor(qm, o);
            }
            float mean = sm * (1.f / 192.f);
            float var  = qm * (1.f / 192.f) - mean * mean;
            float rs = rsqrtf(var + 1e-5f);
            float* ob = out + obase1 + (lbase + r) * D_;
            ob[lane]       = (x0 - mean) * rs * gl[0] + bl[0];
            ob[lane + 64]  = (x1 - mean) * rs * gl[1] + bl[1];
            ob[lane + 128] = (x2 - mean) * rs * gl[2] + bl[2];
        }
        if (shared){
            for (int r = wvi; r < 32; r += 3){
                float x0 = ys2[r * D_ + lane];
                float x1 = ys2[r * D_ + lane + 64];
                float x2 = ys2[r * D_ + lane + 128];
                float sm = x0 + x1 + x2;
                float qm = x0*x0 + x1*x1 + x2*x2;
                #pragma unroll
                for (int o = 32; o > 0; o >>= 1){
                    sm += __shfl_xor(sm, o);
                    qm += __shfl_xor(qm, o);
                }
                float mean = sm * (1.f / 192.f);
                float var  = qm * (1.f / 192.f) - mean * mean;
                float rs = rsqrtf(var + 1e-5f);
                float* ob = out + (size_t)3 * BLD + (lbase + r) * D_;
                ob[lane]       = (x0 - mean) * rs * gl[0] + bl[0];
                ob[lane + 64]  = (x1 - mean) * rs * gl[1] + bl[1];
                ob[lane + 128] = (x2 - mean) * rs * gl[2] + bl[2];
            }
        }
        __syncthreads();
    }
}

extern "C" void kernel_launch(void* const* d_in, const int* in_sizes, int n_in,
                              void* d_out, int out_size, void* d_ws, size_t ws_size,
                              hipStream_t stream)
{
    const float* xr   = (const float*)d_in[0];
    const float* xsr  = (const float*)d_in[1];
    const float* xe   = (const float*)d_in[2];
    const float* xse  = (const float*)d_in[3];
    const float* Wx1  = (const float*)d_in[4];
    const float* Wx2  = (const float*)d_in[5];
    const float* Wxs  = (const float*)d_in[6];
    const float* Wdt1 = (const float*)d_in[7];
    const float* Wdt2 = (const float*)d_in[8];
    const float* Wdts = (const float*)d_in[9];
    const float* bdt1 = (const float*)d_in[10];
    const float* bdt2 = (const float*)d_in[11];
    const float* bdts = (const float*)d_in[12];
    const float* Alog1= (const float*)d_in[13];
    const float* Alog2= (const float*)d_in[14];
    const float* Alogs= (const float*)d_in[15];
    const float* Dp1  = (const float*)d_in[16];
    const float* Dp2  = (const float*)d_in[17];
    const float* Dps  = (const float*)d_in[18];
    // setup_inputs() dict order: g1, g2, gs THEN be1, be2, bes
    const float* g1   = (const float*)d_in[19];
    const float* g2   = (const float*)d_in[20];
    const float* gs   = (const float*)d_in[21];
    const float* be1  = (const float*)d_in[22];
    const float* be2  = (const float*)d_in[23];
    const float* bes  = (const float*)d_in[24];

    float* ws = (float*)d_ws;
    float* out = (float*)d_out;

    const size_t xdbl_f = (size_t)3 * B_ * L_ * K_;          // 1,867,776
    const size_t need128 = (xdbl_f + (size_t)3*B_*128*D_ + (size_t)4*B_*128*D_*N_) * 4;

    proj_kernel<<<dim3(768), dim3(256), 0, stream>>>(xr, xsr, xe, xse, Wx1, Wx2, Wxs, ws);

    if (ws_size >= need128){
        constexpr int NCt = 128;
        float* xdbl = ws;
        float* dsum = xdbl + xdbl_f;
        float* Sbuf = dsum + (size_t)3 * B_ * NCt * D_;
        passA_kernel<NCt><<<dim3(3 * B_ * NCt), dim3(192), 0, stream>>>(xdbl, xr, xe,
            Wdt1, Wdt2, Wdts, bdt1, bdt2, bdts, Alog1, Alog2, Alogs, Sbuf, dsum);
        combine_kernel<NCt><<<dim3(192), dim3(256), 0, stream>>>(Sbuf, dsum, Alog1, Alog2, Alogs);
        passC_kernel<NCt><<<dim3(3 * B_ * NCt), dim3(192), 0, stream>>>(xdbl, xr, xe,
            Wdt1, Wdt2, Wdts, bdt1, bdt2, bdts, Alog1, Alog2, Alogs,
            Dp1, Dp2, Dps, g1, g2, gs, be1, be2, bes, Sbuf, out);
    } else {
        constexpr int NCt = 64;
        float* xdbl = ws;
        float* dsum = xdbl + xdbl_f;
        float* Sbuf = dsum + (size_t)3 * B_ * NCt * D_;
        passA_kernel<NCt><<<dim3(3 * B_ * NCt), dim3(192), 0, stream>>>(xdbl, xr, xe,
            Wdt1, Wdt2, Wdts, bdt1, bdt2, bdts, Alog1, Alog2, Alogs, Sbuf, dsum);
        combine_kernel<NCt><<<dim3(192), dim3(256), 0, stream>>>(Sbuf, dsum, Alog1, Alog2, Alogs);
        passC_kernel<NCt><<<dim3(3 * B_ * NCt), dim3(192), 0, stream>>>(xdbl, xr, xe,
            Wdt1, Wdt2, Wdts, bdt1, bdt2, bdts, Alog1, Alog2, Alogs,
            Dp1, Dp2, Dps, g1, g2, gs, be1, be2, bes, Sbuf, out);
    }
}